// Round 2
// baseline (1602.188 us; speedup 1.0000x reference)
//
#include <hip/hip_runtime.h>
#include <hip/hip_bf16.h>
#include <math.h>

#define D_MODEL 1024
#define FFN_DIM 4096
#define NHEAD 16
#define DK 64
#define BATCH 16
#define SEQ 512
#define ROWS (BATCH * SEQ) /* 8192 */

typedef short short8 __attribute__((ext_vector_type(8)));
typedef float f32x4 __attribute__((ext_vector_type(4)));

__device__ __forceinline__ float bf2f(short s) {
    return __uint_as_float(((unsigned)(unsigned short)s) << 16);
}
__device__ __forceinline__ short f2bf(float f) {
    unsigned u = __float_as_uint(f);
    u += 0x7fff + ((u >> 16) & 1);   // round-to-nearest-even
    return (short)(u >> 16);
}

// ---------------------------------------------------------------------------
// fp32 -> bf16 conversion (weights), vectorized x4
// ---------------------------------------------------------------------------
__global__ __launch_bounds__(256) void conv_f2bf(const float* __restrict__ in,
                                                 short* __restrict__ out, int n) {
    int i = (blockIdx.x * 256 + threadIdx.x) * 4;
    if (i >= n) return;
    float4 v = *(const float4*)(in + i);
    short4 o;
    o.x = f2bf(v.x); o.y = f2bf(v.y); o.z = f2bf(v.z); o.w = f2bf(v.w);
    *(short4*)(out + i) = o;
}

// ---------------------------------------------------------------------------
// LayerNorm over 1024 elems, one block (256 thr) per row, bf16 output
// ---------------------------------------------------------------------------
__global__ __launch_bounds__(256) void ln_kernel(const float* __restrict__ x,
                                                 const float* __restrict__ g,
                                                 const float* __restrict__ beta,
                                                 short* __restrict__ out) {
    const int row = blockIdx.x;
    const int tid = threadIdx.x;
    const float4 xv = ((const float4*)(x + (size_t)row * D_MODEL))[tid];
    float s  = xv.x + xv.y + xv.z + xv.w;
    float s2 = xv.x * xv.x + xv.y * xv.y + xv.z * xv.z + xv.w * xv.w;
#pragma unroll
    for (int off = 32; off >= 1; off >>= 1) {
        s  += __shfl_down(s, off);
        s2 += __shfl_down(s2, off);
    }
    __shared__ float red[8];
    if ((tid & 63) == 0) { red[(tid >> 6) * 2] = s; red[(tid >> 6) * 2 + 1] = s2; }
    __syncthreads();
    s  = red[0] + red[2] + red[4] + red[6];
    s2 = red[1] + red[3] + red[5] + red[7];
    const float mu  = s * (1.0f / D_MODEL);
    const float var = s2 * (1.0f / D_MODEL) - mu * mu;
    const float r   = rsqrtf(var + 1e-5f);
    const int c = tid * 4;
    short4 ov;
    ov.x = f2bf((xv.x - mu) * r * g[c + 0] + beta[c + 0]);
    ov.y = f2bf((xv.y - mu) * r * g[c + 1] + beta[c + 1]);
    ov.z = f2bf((xv.z - mu) * r * g[c + 2] + beta[c + 2]);
    ov.w = f2bf((xv.w - mu) * r * g[c + 3] + beta[c + 3]);
    *(short4*)(out + (size_t)row * D_MODEL + c) = ov;
}

// ---------------------------------------------------------------------------
// bf16 MFMA GEMM, C[M,N] = A[M,K] @ B[K,N], 64x64 tile, 256 threads (4 waves)
// MODE 0: out bf16 (no bias)            -> outb
// MODE 1: out fp32 = acc + bias + resid -> outf
// MODE 2: out bf16 = gelu(acc + bias)   -> outb
// Fragment layouts (HW-verified per guide):
//   A: lane holds A[m=lane&15][k=(lane>>4)*8 + j]
//   B: lane holds B[k=(lane>>4)*8 + j][n=lane&15]
//   C/D: col=lane&15, row=(lane>>4)*4 + reg
// ---------------------------------------------------------------------------
template <int MODE>
__global__ __launch_bounds__(256) void gemm_bf16(
    const short* __restrict__ A, const short* __restrict__ B,
    int M, int N, int K,
    const float* __restrict__ bias, const float* __restrict__ resid,
    float* __restrict__ outf, short* __restrict__ outb) {
    __shared__ __align__(16) short As[64 * 32];
    __shared__ __align__(16) short Bs[64 * 32];  // stored n-major: Bs[n][k]

    const int tid = threadIdx.x;
    const int m0 = blockIdx.y * 64;
    const int n0 = blockIdx.x * 64;

    // A staging map: thread -> (row, 8-elem k chunk)
    const int amm = tid >> 2;
    const int akv = (tid & 3) * 8;
    // B staging map: thread -> (col n, 8-elem k chunk), gathers strided k, writes vector
    const int bnn = tid & 63;
    const int bkq = (tid >> 6) * 8;

    const int w  = tid >> 6;   // wave id: rows w*16..w*16+15
    const int l  = tid & 63;
    const int lm = l & 15;
    const int lq = l >> 4;

    f32x4 acc[4];
#pragma unroll
    for (int i = 0; i < 4; ++i) acc[i] = (f32x4){0.f, 0.f, 0.f, 0.f};

    const short* aptr = A + (size_t)(m0 + amm) * K + akv;

    for (int k0 = 0; k0 < K; k0 += 32) {
        __syncthreads();
        // stage A tile [64][32]
        *(short8*)&As[amm * 32 + akv] = *(const short8*)(aptr + k0);
        // stage B tile transposed to [n][k]
        short tmp[8];
#pragma unroll
        for (int j = 0; j < 8; ++j)
            tmp[j] = B[(size_t)(k0 + bkq + j) * N + n0 + bnn];
        short8 bv;
#pragma unroll
        for (int j = 0; j < 8; ++j) bv[j] = tmp[j];
        *(short8*)&Bs[bnn * 32 + bkq] = bv;
        __syncthreads();

        short8 af = *(short8*)&As[(w * 16 + lm) * 32 + lq * 8];
#pragma unroll
        for (int n4 = 0; n4 < 4; ++n4) {
            short8 bf = *(short8*)&Bs[(n4 * 16 + lm) * 32 + lq * 8];
            acc[n4] = __builtin_amdgcn_mfma_f32_16x16x32_bf16(af, bf, acc[n4], 0, 0, 0);
        }
    }

#pragma unroll
    for (int n4 = 0; n4 < 4; ++n4) {
#pragma unroll
        for (int i = 0; i < 4; ++i) {
            const int row = m0 + w * 16 + lq * 4 + i;
            const int col = n0 + n4 * 16 + lm;
            const float v = acc[n4][i];
            if (MODE == 0) {
                outb[(size_t)row * N + col] = f2bf(v);
            } else if (MODE == 1) {
                outf[(size_t)row * N + col] = v + bias[col] + resid[(size_t)row * N + col];
            } else {
                const float gv = v + bias[col];
                const float ge = 0.5f * gv * (1.0f + erff(gv * 0.70710678118654752f));
                outb[(size_t)row * N + col] = f2bf(ge);
            }
        }
    }
}

// ---------------------------------------------------------------------------
// Causal flash attention. Block = (qtile 64 rows) x head x batch; 256 threads.
// Q/K/V bf16 [ROWS][1024] with head h at cols h*64..h*64+63.
// fp32 online softmax; O accumulator in registers (16 floats/thread).
// ---------------------------------------------------------------------------
__global__ __launch_bounds__(256) void attn_kernel(const short* __restrict__ q,
                                                   const short* __restrict__ k,
                                                   const short* __restrict__ v,
                                                   short* __restrict__ o) {
    __shared__ __align__(16) short Qs[64 * 64];
    __shared__ __align__(16) short Ks[64 * 64];
    __shared__ __align__(16) short Vs[64 * 64];
    __shared__ float S[64 * 64];
    __shared__ float alpha_s[64];
    __shared__ float l_s[64];

    const int tid = threadIdx.x;
    const int qt = blockIdx.x;   // 0..7
    const int h  = blockIdx.y;   // 0..15
    const int b  = blockIdx.z;   // 0..15

    const int qi = tid >> 2;        // 0..63 (row within tile)
    const int c0 = (tid & 3) * 16;  // 16-wide column slab

    // load Q tile once
    {
        const short* src = q + (size_t)(b * SEQ + qt * 64 + qi) * D_MODEL + h * DK + c0;
        *(short8*)&Qs[qi * 64 + c0]     = *(const short8*)src;
        *(short8*)&Qs[qi * 64 + c0 + 8] = *(const short8*)(src + 8);
    }

    float O[16];
#pragma unroll
    for (int i = 0; i < 16; ++i) O[i] = 0.f;
    float m_r = -1e30f, l_r = 0.f;  // softmax state (rows owned by tid<64)

    const float scale = 0.125f;  // 1/sqrt(64)
    const int tq = qt * 64 + qi;

    for (int kt = 0; kt <= qt; ++kt) {
        __syncthreads();  // protect Ks/Vs from previous iteration's readers
        {
            const short* ksrc = k + (size_t)(b * SEQ + kt * 64 + qi) * D_MODEL + h * DK + c0;
            *(short8*)&Ks[qi * 64 + c0]     = *(const short8*)ksrc;
            *(short8*)&Ks[qi * 64 + c0 + 8] = *(const short8*)(ksrc + 8);
            const short* vsrc = v + (size_t)(b * SEQ + kt * 64 + qi) * D_MODEL + h * DK + c0;
            *(short8*)&Vs[qi * 64 + c0]     = *(const short8*)vsrc;
            *(short8*)&Vs[qi * 64 + c0 + 8] = *(const short8*)(vsrc + 8);
        }
        __syncthreads();

        // S[qi][c0..c0+15] = Q[qi] . K[c0+jj]
        float acc[16];
#pragma unroll
        for (int jj = 0; jj < 16; ++jj) acc[jj] = 0.f;
        for (int d = 0; d < 64; ++d) {
            const float qv = bf2f(Qs[qi * 64 + d]);
#pragma unroll
            for (int jj = 0; jj < 16; ++jj)
                acc[jj] += qv * bf2f(Ks[(c0 + jj) * 64 + d]);
        }
#pragma unroll
        for (int jj = 0; jj < 16; ++jj) {
            const int tk = kt * 64 + c0 + jj;
            S[qi * 64 + c0 + jj] = (tk <= tq) ? acc[jj] * scale : -1e30f;
        }
        __syncthreads();

        // online softmax: thread t<64 owns row t
        if (tid < 64) {
            float mnew = m_r;
            for (int j = 0; j < 64; ++j) mnew = fmaxf(mnew, S[tid * 64 + j]);
            const float al = __expf(m_r - mnew);
            float sum = 0.f;
            for (int j = 0; j < 64; ++j) {
                const float p = __expf(S[tid * 64 + j] - mnew);
                S[tid * 64 + j] = p;
                sum += p;
            }
            l_r = l_r * al + sum;
            m_r = mnew;
            alpha_s[tid] = al;
            l_s[tid] = l_r;
        }
        __syncthreads();

        // O[qi][c0..c0+15] accumulate
        const float al = alpha_s[qi];
#pragma unroll
        for (int dd = 0; dd < 16; ++dd) O[dd] *= al;
        for (int j = 0; j < 64; ++j) {
            const float p = S[qi * 64 + j];
#pragma unroll
            for (int dd = 0; dd < 16; ++dd)
                O[dd] += p * bf2f(Vs[j * 64 + c0 + dd]);
        }
    }
    __syncthreads();
    const float invl = 1.0f / l_s[qi];
    short* dst = o + (size_t)(b * SEQ + tq) * D_MODEL + h * DK + c0;
#pragma unroll
    for (int dd = 0; dd < 16; ++dd) dst[dd] = f2bf(O[dd] * invl);
}

// ---------------------------------------------------------------------------
// launcher
// ---------------------------------------------------------------------------
extern "C" void kernel_launch(void* const* d_in, const int* in_sizes, int n_in,
                              void* d_out, int out_size, void* d_ws, size_t ws_size,
                              hipStream_t stream) {
    const float* x     = (const float*)d_in[0];
    const float* ln1_g = (const float*)d_in[1];
    const float* ln1_b = (const float*)d_in[2];
    const float* w_q   = (const float*)d_in[3];
    const float* w_k   = (const float*)d_in[4];
    const float* w_v   = (const float*)d_in[5];
    const float* w_o   = (const float*)d_in[6];
    const float* b_o   = (const float*)d_in[7];
    const float* ln2_g = (const float*)d_in[8];
    const float* ln2_b = (const float*)d_in[9];
    const float* w1    = (const float*)d_in[10];
    const float* b1    = (const float*)d_in[11];
    const float* w2    = (const float*)d_in[12];
    const float* b2    = (const float*)d_in[13];
    float* out = (float*)d_out;

    char* ws = (char*)d_ws;
    size_t off = 0;
    auto alloc = [&](size_t bytes) {
        char* p = ws + off;
        off += (bytes + 255) & ~(size_t)255;
        return p;
    };
    // activation buffers (q/k/v/a region is reused as the [8192,4096] FFN1 output)
    short* h_bf  = (short*)alloc((size_t)ROWS * D_MODEL * 2);   // 16 MB
    short* q_bf  = (short*)alloc((size_t)ROWS * D_MODEL * 2);   // 16 MB (g1_bf aliases from here)
    short* k_bf  = (short*)alloc((size_t)ROWS * D_MODEL * 2);   // 16 MB
    short* v_bf  = (short*)alloc((size_t)ROWS * D_MODEL * 2);   // 16 MB
    short* a_bf  = (short*)alloc((size_t)ROWS * D_MODEL * 2);   // 16 MB
    float* x1    = (float*)alloc((size_t)ROWS * D_MODEL * 4);   // 32 MB
    short* wq_bf = (short*)alloc((size_t)D_MODEL * D_MODEL * 2);
    short* wk_bf = (short*)alloc((size_t)D_MODEL * D_MODEL * 2);
    short* wv_bf = (short*)alloc((size_t)D_MODEL * D_MODEL * 2);
    short* wo_bf = (short*)alloc((size_t)D_MODEL * D_MODEL * 2);
    short* w1_bf = (short*)alloc((size_t)D_MODEL * FFN_DIM * 2);
    short* w2_bf = (short*)alloc((size_t)FFN_DIM * D_MODEL * 2);
    short* g1_bf = q_bf;  // [8192,4096] bf16, aliases q/k/v/a after attention is done

    // weight conversions (ws is re-poisoned each launch, so must re-run)
    conv_f2bf<<<1024, 256, 0, stream>>>(w_q, wq_bf, D_MODEL * D_MODEL);
    conv_f2bf<<<1024, 256, 0, stream>>>(w_k, wk_bf, D_MODEL * D_MODEL);
    conv_f2bf<<<1024, 256, 0, stream>>>(w_v, wv_bf, D_MODEL * D_MODEL);
    conv_f2bf<<<1024, 256, 0, stream>>>(w_o, wo_bf, D_MODEL * D_MODEL);
    conv_f2bf<<<4096, 256, 0, stream>>>(w1, w1_bf, D_MODEL * FFN_DIM);
    conv_f2bf<<<4096, 256, 0, stream>>>(w2, w2_bf, FFN_DIM * D_MODEL);

    // LN1
    ln_kernel<<<ROWS, 256, 0, stream>>>(x, ln1_g, ln1_b, h_bf);

    // Q, K, V projections
    dim3 g1024(D_MODEL / 64, ROWS / 64);
    gemm_bf16<0><<<g1024, 256, 0, stream>>>(h_bf, wq_bf, ROWS, D_MODEL, D_MODEL,
                                            nullptr, nullptr, nullptr, q_bf);
    gemm_bf16<0><<<g1024, 256, 0, stream>>>(h_bf, wk_bf, ROWS, D_MODEL, D_MODEL,
                                            nullptr, nullptr, nullptr, k_bf);
    gemm_bf16<0><<<g1024, 256, 0, stream>>>(h_bf, wv_bf, ROWS, D_MODEL, D_MODEL,
                                            nullptr, nullptr, nullptr, v_bf);

    // attention
    attn_kernel<<<dim3(SEQ / 64, NHEAD, BATCH), 256, 0, stream>>>(q_bf, k_bf, v_bf, a_bf);

    // output projection + bias + residual -> x1 (fp32)
    gemm_bf16<1><<<g1024, 256, 0, stream>>>(a_bf, wo_bf, ROWS, D_MODEL, D_MODEL,
                                            b_o, x, x1, nullptr);

    // LN2
    ln_kernel<<<ROWS, 256, 0, stream>>>(x1, ln2_g, ln2_b, h_bf);

    // FFN1 + gelu -> g1_bf (bf16)
    dim3 g4096(FFN_DIM / 64, ROWS / 64);
    gemm_bf16<2><<<g4096, 256, 0, stream>>>(h_bf, w1_bf, ROWS, FFN_DIM, D_MODEL,
                                            b1, nullptr, nullptr, g1_bf);

    // FFN2 + bias + residual -> out (fp32)
    gemm_bf16<1><<<g1024, 256, 0, stream>>>(g1_bf, w2_bf, ROWS, D_MODEL, FFN_DIM,
                                            b2, x1, out, nullptr);
}

// Round 3
// 574.440 us; speedup vs baseline: 2.7891x; 2.7891x over previous
//
#include <hip/hip_runtime.h>
#include <hip/hip_bf16.h>
#include <math.h>

#define D_MODEL 1024
#define FFN_DIM 4096
#define NHEAD 16
#define DK 64
#define BATCH 16
#define SEQ 512
#define ROWS (BATCH * SEQ) /* 8192 */

typedef short short8 __attribute__((ext_vector_type(8)));
typedef float f32x4 __attribute__((ext_vector_type(4)));

__device__ __forceinline__ float bf2f(short s) {
    return __uint_as_float(((unsigned)(unsigned short)s) << 16);
}
__device__ __forceinline__ short f2bf(float f) {
    unsigned u = __float_as_uint(f);
    u += 0x7fff + ((u >> 16) & 1);   // round-to-nearest-even
    return (short)(u >> 16);
}

// XOR-swizzled index into a [rows][64] bf16 tile: keeps 8-elem blocks contiguous
// (so b128 frag reads stay vectorizable) while spreading banks across rows.
__device__ __forceinline__ int swz(int row, int col) {
    int s = (row ^ (row >> 3)) & 7;
    return row * 64 + ((((col >> 3) ^ s) << 3) | (col & 7));
}

// async 16B global -> LDS (wave-uniform LDS base + lane*16)
__device__ __forceinline__ void gll16(const short* g, short* l) {
    __builtin_amdgcn_global_load_lds(
        (const __attribute__((address_space(1))) unsigned int*)g,
        (__attribute__((address_space(3))) unsigned int*)l, 16, 0, 0);
}

// ---------------------------------------------------------------------------
// fused fp32->bf16 convert + transpose: in[K][N] fp32 -> out[N][K] bf16
// 64x64 tiles, swizzled LDS staging.
// ---------------------------------------------------------------------------
__global__ __launch_bounds__(256) void convT(const float* __restrict__ in,
                                             short* __restrict__ out,
                                             int K, int N) {
    __shared__ short t[64 * 64];
    const int tid = threadIdx.x;
    const int k0 = blockIdx.y * 64, n0 = blockIdx.x * 64;
    {
        const int r = tid >> 4;           // 0..15
        const int c4 = (tid & 15) * 4;    // 0..60
#pragma unroll
        for (int i = 0; i < 4; ++i) {
            const int row = i * 16 + r;   // k-local
            float4 vv = *(const float4*)&in[(size_t)(k0 + row) * N + n0 + c4];
            t[swz(row, c4 + 0)] = f2bf(vv.x);
            t[swz(row, c4 + 1)] = f2bf(vv.y);
            t[swz(row, c4 + 2)] = f2bf(vv.z);
            t[swz(row, c4 + 3)] = f2bf(vv.w);
        }
    }
    __syncthreads();
    {
        const int n = tid >> 2;           // 0..63
        const int kc = (tid & 3) * 16;
        short tmp[16];
#pragma unroll
        for (int kk = 0; kk < 16; ++kk) tmp[kk] = t[swz(kc + kk, n)];
        short8 s0, s1;
#pragma unroll
        for (int j = 0; j < 8; ++j) { s0[j] = tmp[j]; s1[j] = tmp[8 + j]; }
        short* dst = &out[(size_t)(n0 + n) * K + k0 + kc];
        *(short8*)dst = s0;
        *(short8*)(dst + 8) = s1;
    }
}

// ---------------------------------------------------------------------------
// LayerNorm over 1024 elems, one block (256 thr) per row, bf16 output
// ---------------------------------------------------------------------------
__global__ __launch_bounds__(256) void ln_kernel(const float* __restrict__ x,
                                                 const float* __restrict__ g,
                                                 const float* __restrict__ beta,
                                                 short* __restrict__ out) {
    const int row = blockIdx.x;
    const int tid = threadIdx.x;
    const float4 xv = ((const float4*)(x + (size_t)row * D_MODEL))[tid];
    float s  = xv.x + xv.y + xv.z + xv.w;
    float s2 = xv.x * xv.x + xv.y * xv.y + xv.z * xv.z + xv.w * xv.w;
#pragma unroll
    for (int off = 32; off >= 1; off >>= 1) {
        s  += __shfl_down(s, off);
        s2 += __shfl_down(s2, off);
    }
    __shared__ float red[8];
    if ((tid & 63) == 0) { red[(tid >> 6) * 2] = s; red[(tid >> 6) * 2 + 1] = s2; }
    __syncthreads();
    s  = red[0] + red[2] + red[4] + red[6];
    s2 = red[1] + red[3] + red[5] + red[7];
    const float mu  = s * (1.0f / D_MODEL);
    const float var = s2 * (1.0f / D_MODEL) - mu * mu;
    const float r   = rsqrtf(var + 1e-5f);
    const int c = tid * 4;
    short4 ov;
    ov.x = f2bf((xv.x - mu) * r * g[c + 0] + beta[c + 0]);
    ov.y = f2bf((xv.y - mu) * r * g[c + 1] + beta[c + 1]);
    ov.z = f2bf((xv.z - mu) * r * g[c + 2] + beta[c + 2]);
    ov.w = f2bf((xv.w - mu) * r * g[c + 3] + beta[c + 3]);
    *(short4*)(out + (size_t)row * D_MODEL + c) = ov;
}

// ---------------------------------------------------------------------------
// m97-class bf16 MFMA GEMM: C[M,N] = A[M,K] @ Bt[N,K]^T
// 128x128 tile, 256 thr (4 waves, 2x2 wave grid, 4x4 16x16 accs each),
// BK=32, global_load_lds width=16 staging, 2-barrier K-loop.
// MODE 0: out bf16                      -> outb
// MODE 1: out fp32 = acc + bias + resid -> outf
// MODE 2: out bf16 = gelu(acc + bias)   -> outb
// ---------------------------------------------------------------------------
template <int MODE>
__global__ __launch_bounds__(256) void gemm128(
    const short* __restrict__ A, const short* __restrict__ Bt,
    int M, int N, int K,
    const float* __restrict__ bias, const float* __restrict__ resid,
    float* __restrict__ outf, short* __restrict__ outb) {
    __shared__ __align__(16) short As[128 * 32];
    __shared__ __align__(16) short Bs[128 * 32];
    const int tid = threadIdx.x;
    const int w = tid >> 6, lane = tid & 63;
    const int lm = lane & 15, quad = lane >> 4;
    const int m0 = blockIdx.y * 128, n0 = blockIdx.x * 128;
    const int wm = (w & 1) * 64, wn = (w >> 1) * 64;

    // staging: wave w covers 16-row chunks w and w+4; lane -> (row, 8-elem k)
    const int srow = w * 16 + (lane >> 2);
    const int skk  = (lane & 3) * 8;
    const short* gA0 = A  + (size_t)(m0 + srow) * K + skk;
    const short* gA1 = gA0 + (size_t)64 * K;
    const short* gB0 = Bt + (size_t)(n0 + srow) * K + skk;
    const short* gB1 = gB0 + (size_t)64 * K;
    short* lA0 = &As[w * 512];
    short* lA1 = &As[(4 + w) * 512];
    short* lB0 = &Bs[w * 512];
    short* lB1 = &Bs[(4 + w) * 512];

    f32x4 acc[4][4];
#pragma unroll
    for (int i = 0; i < 4; ++i)
#pragma unroll
        for (int j = 0; j < 4; ++j) acc[i][j] = (f32x4){0.f, 0.f, 0.f, 0.f};

    for (int k0 = 0; k0 < K; k0 += 32) {
        __syncthreads();
        gll16(gA0 + k0, lA0);
        gll16(gA1 + k0, lA1);
        gll16(gB0 + k0, lB0);
        gll16(gB1 + k0, lB1);
        __syncthreads();
        short8 af[4], bfr[4];
#pragma unroll
        for (int mm = 0; mm < 4; ++mm)
            af[mm] = *(short8*)&As[(wm + mm * 16 + lm) * 32 + quad * 8];
#pragma unroll
        for (int nn = 0; nn < 4; ++nn)
            bfr[nn] = *(short8*)&Bs[(wn + nn * 16 + lm) * 32 + quad * 8];
#pragma unroll
        for (int mm = 0; mm < 4; ++mm)
#pragma unroll
            for (int nn = 0; nn < 4; ++nn)
                acc[mm][nn] = __builtin_amdgcn_mfma_f32_16x16x32_bf16(
                    af[mm], bfr[nn], acc[mm][nn], 0, 0, 0);
    }

#pragma unroll
    for (int mm = 0; mm < 4; ++mm)
#pragma unroll
        for (int nn = 0; nn < 4; ++nn)
#pragma unroll
            for (int r = 0; r < 4; ++r) {
                const int row = m0 + wm + mm * 16 + quad * 4 + r;
                const int col = n0 + wn + nn * 16 + lm;
                const float vv = acc[mm][nn][r];
                if (MODE == 0) {
                    outb[(size_t)row * N + col] = f2bf(vv);
                } else if (MODE == 1) {
                    outf[(size_t)row * N + col] =
                        vv + bias[col] + resid[(size_t)row * N + col];
                } else {
                    const float gv = vv + bias[col];
                    const float ge = 0.5f * gv * (1.0f + erff(gv * 0.70710678118654752f));
                    outb[(size_t)row * N + col] = f2bf(ge);
                }
            }
}

// ---------------------------------------------------------------------------
// MFMA causal flash attention. Block = 64 q-rows x head x batch, 256 thr.
// Wave w owns q rows w*16..w*16+15. QK^T and PV via mfma_f32_16x16x32_bf16.
// Online softmax in registers (C-layout rows match across S, O, m/l state).
// P converts C-layout -> A-layout via per-wave swizzled LDS round-trip.
// ---------------------------------------------------------------------------
__global__ __launch_bounds__(256) void attn_mfma(const short* __restrict__ q,
                                                 const short* __restrict__ k,
                                                 const short* __restrict__ v,
                                                 short* __restrict__ o) {
    __shared__ __align__(16) short Ks[64 * 64];   // [j][d] swizzled
    __shared__ __align__(16) short Vt[64 * 64];   // [d][j] swizzled
    __shared__ __align__(16) short Ps[4 * 16 * 64]; // per-wave [m][j] swizzled

    const int tid = threadIdx.x;
    const int qt = blockIdx.x, h = blockIdx.y, b = blockIdx.z;
    const int w = tid >> 6, lane = tid & 63;
    const int lm = lane & 15, quad = lane >> 4;

    const int sj  = tid >> 2;          // staging row 0..63
    const int sd0 = (tid & 3) * 16;    // staging d-chunk

    // Q A-frags for this wave's 16 rows, pre-scaled by 1/sqrt(64)=0.125 (exact)
    short8 aq[2];
    {
        const short* qrow = q + (size_t)(b * SEQ + qt * 64 + w * 16 + lm) * D_MODEL + h * DK;
#pragma unroll
        for (int kk = 0; kk < 2; ++kk) {
            short8 raw = *(const short8*)(qrow + kk * 32 + quad * 8);
            short8 sc;
#pragma unroll
            for (int j = 0; j < 8; ++j) sc[j] = f2bf(bf2f(raw[j]) * 0.125f);
            aq[kk] = sc;
        }
    }

    f32x4 accO[4];
#pragma unroll
    for (int i = 0; i < 4; ++i) accO[i] = (f32x4){0.f, 0.f, 0.f, 0.f};
    float mrow[4] = {-1e30f, -1e30f, -1e30f, -1e30f};
    float lrow[4] = {0.f, 0.f, 0.f, 0.f};

    short* pw = &Ps[w * 1024];

    for (int kt = 0; kt <= qt; ++kt) {
        __syncthreads();   // previous iteration's Ks/Vt readers done
        {
            const short* ksrc = k + (size_t)(b * SEQ + kt * 64 + sj) * D_MODEL + h * DK + sd0;
            short8 k0v = *(const short8*)ksrc;
            short8 k1v = *(const short8*)(ksrc + 8);
            *(short8*)&Ks[swz(sj, sd0)]     = k0v;
            *(short8*)&Ks[swz(sj, sd0 + 8)] = k1v;
            const short* vsrc = v + (size_t)(b * SEQ + kt * 64 + sj) * D_MODEL + h * DK + sd0;
            short8 v0v = *(const short8*)vsrc;
            short8 v1v = *(const short8*)(vsrc + 8);
#pragma unroll
            for (int dd = 0; dd < 8; ++dd) Vt[swz(sd0 + dd, sj)]     = v0v[dd];
#pragma unroll
            for (int dd = 0; dd < 8; ++dd) Vt[swz(sd0 + 8 + dd, sj)] = v1v[dd];
        }
        __syncthreads();

        // S = (Q*scale) K^T : wave rows 16 x 64 cols
        f32x4 sacc[4];
#pragma unroll
        for (int nn = 0; nn < 4; ++nn) sacc[nn] = (f32x4){0.f, 0.f, 0.f, 0.f};
#pragma unroll
        for (int kk = 0; kk < 2; ++kk)
#pragma unroll
            for (int nn = 0; nn < 4; ++nn) {
                short8 bfrag = *(short8*)&Ks[swz(nn * 16 + lm, kk * 32 + quad * 8)];
                sacc[nn] = __builtin_amdgcn_mfma_f32_16x16x32_bf16(
                    aq[kk], bfrag, sacc[nn], 0, 0, 0);
            }

        if (kt == qt) {   // diagonal tile: causal mask
#pragma unroll
            for (int nn = 0; nn < 4; ++nn) {
                const int kg = nn * 16 + lm;
#pragma unroll
                for (int r = 0; r < 4; ++r) {
                    const int qg = w * 16 + quad * 4 + r;
                    if (kg > qg) sacc[nn][r] = -1e30f;
                }
            }
        }

        // row max (over 4 chunks in-register, then across 16 lanes of the quad)
        float mnew[4], alpha[4], rsum[4];
#pragma unroll
        for (int r = 0; r < 4; ++r) {
            float mx = fmaxf(fmaxf(sacc[0][r], sacc[1][r]), fmaxf(sacc[2][r], sacc[3][r]));
#pragma unroll
            for (int msk = 1; msk <= 8; msk <<= 1) mx = fmaxf(mx, __shfl_xor(mx, msk));
            mnew[r] = fmaxf(mrow[r], mx);
            alpha[r] = __expf(mrow[r] - mnew[r]);
            rsum[r] = 0.f;
        }
        // P = exp(S - mnew), row sums
#pragma unroll
        for (int nn = 0; nn < 4; ++nn)
#pragma unroll
            for (int r = 0; r < 4; ++r) {
                const float p = __expf(sacc[nn][r] - mnew[r]);
                sacc[nn][r] = p;
                rsum[r] += p;
            }
#pragma unroll
        for (int r = 0; r < 4; ++r) {
#pragma unroll
            for (int msk = 1; msk <= 8; msk <<= 1) rsum[r] += __shfl_xor(rsum[r], msk);
            lrow[r] = lrow[r] * alpha[r] + rsum[r];
            mrow[r] = mnew[r];
        }
        // rescale O accumulators
#pragma unroll
        for (int nn = 0; nn < 4; ++nn)
#pragma unroll
            for (int r = 0; r < 4; ++r) accO[nn][r] *= alpha[r];

        // P (bf16) -> per-wave LDS in A-layout source form
#pragma unroll
        for (int nn = 0; nn < 4; ++nn)
#pragma unroll
            for (int r = 0; r < 4; ++r)
                pw[swz(quad * 4 + r, nn * 16 + lm)] = f2bf(sacc[nn][r]);

        // O += P V
#pragma unroll
        for (int kk = 0; kk < 2; ++kk) {
            short8 afrag = *(short8*)&pw[swz(lm, kk * 32 + quad * 8)];
#pragma unroll
            for (int nn = 0; nn < 4; ++nn) {
                short8 bfrag = *(short8*)&Vt[swz(nn * 16 + lm, kk * 32 + quad * 8)];
                accO[nn] = __builtin_amdgcn_mfma_f32_16x16x32_bf16(
                    afrag, bfrag, accO[nn], 0, 0, 0);
            }
        }
    }

    // epilogue: O / l -> bf16
#pragma unroll
    for (int r = 0; r < 4; ++r) {
        const float invl = 1.0f / lrow[r];
        const int row = b * SEQ + qt * 64 + w * 16 + quad * 4 + r;
#pragma unroll
        for (int nn = 0; nn < 4; ++nn)
            o[(size_t)row * D_MODEL + h * DK + nn * 16 + lm] = f2bf(accO[nn][r] * invl);
    }
}

// ---------------------------------------------------------------------------
// launcher
// ---------------------------------------------------------------------------
extern "C" void kernel_launch(void* const* d_in, const int* in_sizes, int n_in,
                              void* d_out, int out_size, void* d_ws, size_t ws_size,
                              hipStream_t stream) {
    const float* x     = (const float*)d_in[0];
    const float* ln1_g = (const float*)d_in[1];
    const float* ln1_b = (const float*)d_in[2];
    const float* w_q   = (const float*)d_in[3];
    const float* w_k   = (const float*)d_in[4];
    const float* w_v   = (const float*)d_in[5];
    const float* w_o   = (const float*)d_in[6];
    const float* b_o   = (const float*)d_in[7];
    const float* ln2_g = (const float*)d_in[8];
    const float* ln2_b = (const float*)d_in[9];
    const float* w1    = (const float*)d_in[10];
    const float* b1    = (const float*)d_in[11];
    const float* w2    = (const float*)d_in[12];
    const float* b2    = (const float*)d_in[13];
    float* out = (float*)d_out;

    char* ws = (char*)d_ws;
    size_t off = 0;
    auto alloc = [&](size_t bytes) {
        char* p = ws + off;
        off += (bytes + 255) & ~(size_t)255;
        return p;
    };
    short* h_bf  = (short*)alloc((size_t)ROWS * D_MODEL * 2);   // 16 MB
    short* q_bf  = (short*)alloc((size_t)ROWS * D_MODEL * 2);   // 16 MB (g1_bf starts here)
    short* k_bf  = (short*)alloc((size_t)ROWS * D_MODEL * 2);   // 16 MB
    short* v_bf  = (short*)alloc((size_t)ROWS * D_MODEL * 2);   // 16 MB
    short* a_bf  = (short*)alloc((size_t)ROWS * D_MODEL * 2);   // 16 MB
    float* x1    = (float*)alloc((size_t)ROWS * D_MODEL * 4);   // 32 MB
    short* wqT   = (short*)alloc((size_t)D_MODEL * D_MODEL * 2);
    short* wkT   = (short*)alloc((size_t)D_MODEL * D_MODEL * 2);
    short* wvT   = (short*)alloc((size_t)D_MODEL * D_MODEL * 2);
    short* woT   = (short*)alloc((size_t)D_MODEL * D_MODEL * 2);
    short* w1T   = (short*)alloc((size_t)D_MODEL * FFN_DIM * 2);
    short* w2T   = (short*)alloc((size_t)FFN_DIM * D_MODEL * 2);
    short* g1_bf = q_bf;  // [8192,4096] bf16 aliases q/k/v/a after attention

    // weight convert+transpose ([K][N] fp32 -> [N][K] bf16); re-run every launch
    convT<<<dim3(16, 16), 256, 0, stream>>>(w_q, wqT, D_MODEL, D_MODEL);
    convT<<<dim3(16, 16), 256, 0, stream>>>(w_k, wkT, D_MODEL, D_MODEL);
    convT<<<dim3(16, 16), 256, 0, stream>>>(w_v, wvT, D_MODEL, D_MODEL);
    convT<<<dim3(16, 16), 256, 0, stream>>>(w_o, woT, D_MODEL, D_MODEL);
    convT<<<dim3(64, 16), 256, 0, stream>>>(w1, w1T, D_MODEL, FFN_DIM);
    convT<<<dim3(16, 64), 256, 0, stream>>>(w2, w2T, FFN_DIM, D_MODEL);

    // LN1
    ln_kernel<<<ROWS, 256, 0, stream>>>(x, ln1_g, ln1_b, h_bf);

    // Q, K, V projections
    dim3 gQKV(D_MODEL / 128, ROWS / 128);
    gemm128<0><<<gQKV, 256, 0, stream>>>(h_bf, wqT, ROWS, D_MODEL, D_MODEL,
                                         nullptr, nullptr, nullptr, q_bf);
    gemm128<0><<<gQKV, 256, 0, stream>>>(h_bf, wkT, ROWS, D_MODEL, D_MODEL,
                                         nullptr, nullptr, nullptr, k_bf);
    gemm128<0><<<gQKV, 256, 0, stream>>>(h_bf, wvT, ROWS, D_MODEL, D_MODEL,
                                         nullptr, nullptr, nullptr, v_bf);

    // attention
    attn_mfma<<<dim3(SEQ / 64, NHEAD, BATCH), 256, 0, stream>>>(q_bf, k_bf, v_bf, a_bf);

    // output projection + bias + residual -> x1 (fp32)
    gemm128<1><<<gQKV, 256, 0, stream>>>(a_bf, woT, ROWS, D_MODEL, D_MODEL,
                                         b_o, x, x1, nullptr);

    // LN2
    ln_kernel<<<ROWS, 256, 0, stream>>>(x1, ln2_g, ln2_b, h_bf);

    // FFN1 + exact GELU -> g1_bf
    gemm128<2><<<dim3(FFN_DIM / 128, ROWS / 128), 256, 0, stream>>>(
        h_bf, w1T, ROWS, FFN_DIM, D_MODEL, b1, nullptr, nullptr, g1_bf);

    // FFN2 + bias + residual -> out
    gemm128<1><<<dim3(D_MODEL / 128, ROWS / 128), 256, 0, stream>>>(
        g1_bf, w2T, ROWS, D_MODEL, FFN_DIM, b2, x1, out, nullptr);
}

// Round 4
// 530.866 us; speedup vs baseline: 3.0181x; 1.0821x over previous
//
#include <hip/hip_runtime.h>
#include <hip/hip_bf16.h>
#include <math.h>

#define D_MODEL 1024
#define FFN_DIM 4096
#define NHEAD 16
#define DK 64
#define BATCH 16
#define SEQ 512
#define ROWS (BATCH * SEQ) /* 8192 */
#define QKV_N 3072

typedef short short8 __attribute__((ext_vector_type(8)));
typedef float f32x4 __attribute__((ext_vector_type(4)));

__device__ __forceinline__ float bf2f(short s) {
    return __uint_as_float(((unsigned)(unsigned short)s) << 16);
}
__device__ __forceinline__ short f2bf(float f) {
    unsigned u = __float_as_uint(f);
    u += 0x7fff + ((u >> 16) & 1);   // round-to-nearest-even
    return (short)(u >> 16);
}

// XOR-swizzled index into a [rows][64] bf16 tile (8-elem blocks kept contiguous)
__device__ __forceinline__ int swz(int row, int col) {
    int s = (row ^ (row >> 3)) & 7;
    return row * 64 + ((((col >> 3) ^ s) << 3) | (col & 7));
}

// async 16B global -> LDS (wave-uniform LDS base + lane*16)
__device__ __forceinline__ void gll16(const short* g, short* l) {
    __builtin_amdgcn_global_load_lds(
        (const __attribute__((address_space(1))) unsigned int*)g,
        (__attribute__((address_space(3))) unsigned int*)l, 16, 0, 0);
}

// ---------------------------------------------------------------------------
// fused fp32->bf16 convert + transpose: in[K][N] fp32 -> out[N][K] bf16
// ---------------------------------------------------------------------------
__global__ __launch_bounds__(256) void convT(const float* __restrict__ in,
                                             short* __restrict__ out,
                                             int K, int N) {
    __shared__ short t[64 * 64];
    const int tid = threadIdx.x;
    const int k0 = blockIdx.y * 64, n0 = blockIdx.x * 64;
    {
        const int r = tid >> 4;           // 0..15
        const int c4 = (tid & 15) * 4;    // 0..60
#pragma unroll
        for (int i = 0; i < 4; ++i) {
            const int row = i * 16 + r;   // k-local
            float4 vv = *(const float4*)&in[(size_t)(k0 + row) * N + n0 + c4];
            t[swz(row, c4 + 0)] = f2bf(vv.x);
            t[swz(row, c4 + 1)] = f2bf(vv.y);
            t[swz(row, c4 + 2)] = f2bf(vv.z);
            t[swz(row, c4 + 3)] = f2bf(vv.w);
        }
    }
    __syncthreads();
    {
        const int n = tid >> 2;           // 0..63
        const int kc = (tid & 3) * 16;
        short tmp[16];
#pragma unroll
        for (int kk = 0; kk < 16; ++kk) tmp[kk] = t[swz(kc + kk, n)];
        short8 s0, s1;
#pragma unroll
        for (int j = 0; j < 8; ++j) { s0[j] = tmp[j]; s1[j] = tmp[8 + j]; }
        short* dst = &out[(size_t)(n0 + n) * K + k0 + kc];
        *(short8*)dst = s0;
        *(short8*)(dst + 8) = s1;
    }
}

// ---------------------------------------------------------------------------
// LayerNorm over 1024 elems, one block (256 thr) per row, bf16 output
// ---------------------------------------------------------------------------
__global__ __launch_bounds__(256) void ln_kernel(const float* __restrict__ x,
                                                 const float* __restrict__ g,
                                                 const float* __restrict__ beta,
                                                 short* __restrict__ out) {
    const int row = blockIdx.x;
    const int tid = threadIdx.x;
    const float4 xv = ((const float4*)(x + (size_t)row * D_MODEL))[tid];
    float s  = xv.x + xv.y + xv.z + xv.w;
    float s2 = xv.x * xv.x + xv.y * xv.y + xv.z * xv.z + xv.w * xv.w;
#pragma unroll
    for (int off = 32; off >= 1; off >>= 1) {
        s  += __shfl_down(s, off);
        s2 += __shfl_down(s2, off);
    }
    __shared__ float red[8];
    if ((tid & 63) == 0) { red[(tid >> 6) * 2] = s; red[(tid >> 6) * 2 + 1] = s2; }
    __syncthreads();
    s  = red[0] + red[2] + red[4] + red[6];
    s2 = red[1] + red[3] + red[5] + red[7];
    const float mu  = s * (1.0f / D_MODEL);
    const float var = s2 * (1.0f / D_MODEL) - mu * mu;
    const float r   = rsqrtf(var + 1e-5f);
    const int c = tid * 4;
    short4 ov;
    ov.x = f2bf((xv.x - mu) * r * g[c + 0] + beta[c + 0]);
    ov.y = f2bf((xv.y - mu) * r * g[c + 1] + beta[c + 1]);
    ov.z = f2bf((xv.z - mu) * r * g[c + 2] + beta[c + 2]);
    ov.w = f2bf((xv.w - mu) * r * g[c + 3] + beta[c + 3]);
    *(short4*)(out + (size_t)row * D_MODEL + c) = ov;
}

// ---------------------------------------------------------------------------
// bf16 MFMA GEMM: C[M,N] = A[M,K] @ Bt[N,K]^T. 128x128 tile, 4 waves,
// BK=64, XOR-swizzled LDS chunks (16B granularity) compatible with
// global_load_lds lane-contiguity; one barrier pair per 64-k.
// LDS chunk layout: tile[row][kchunk] stored at chunk index row*8 + (kchunk^(row&7)).
// MODE 0: out bf16; MODE 1: fp32 = acc+bias+resid; MODE 2: bf16 = gelu_tanh(acc+bias)
// ---------------------------------------------------------------------------
template <int MODE>
__global__ __launch_bounds__(256) void gemm128(
    const short* __restrict__ A, const short* __restrict__ Bt,
    int M, int N, int K, int ldc,
    const float* __restrict__ bias, const float* __restrict__ resid,
    float* __restrict__ outf, short* __restrict__ outb) {
    __shared__ __align__(16) short As[128 * 64];
    __shared__ __align__(16) short Bs[128 * 64];
    const int tid = threadIdx.x;
    const int w = tid >> 6, lane = tid & 63;
    const int lm = lane & 15, quad = lane >> 4;
    const int m0 = blockIdx.y * 128, n0 = blockIdx.x * 128;
    const int wm = (w & 1) * 64, wn = (w >> 1) * 64;

    // staging: call j covers rows j*32 + w*8 .. +7, lane -> (row_local=lane>>3,
    // lds chunk = lane&7). Global k-chunk is XOR-permuted so LDS dest stays
    // lane-contiguous while storage is swizzled.
    const int srl = lane >> 3;                  // 0..7 row within 8-row group
    const int gch = (lane & 7) ^ srl;           // global k-chunk this lane fetches
    const short* gA[4];
    const short* gB[4];
    short* lA[4];
    short* lB[4];
#pragma unroll
    for (int j = 0; j < 4; ++j) {
        const int row = j * 32 + w * 8 + srl;
        gA[j] = A  + (size_t)(m0 + row) * K + gch * 8;
        gB[j] = Bt + (size_t)(n0 + row) * K + gch * 8;
        lA[j] = &As[(j * 32 + w * 8) * 64];
        lB[j] = &Bs[(j * 32 + w * 8) * 64];
    }

    f32x4 acc[4][4];
#pragma unroll
    for (int i = 0; i < 4; ++i)
#pragma unroll
        for (int j = 0; j < 4; ++j) acc[i][j] = (f32x4){0.f, 0.f, 0.f, 0.f};

    for (int k0 = 0; k0 < K; k0 += 64) {
        __syncthreads();
#pragma unroll
        for (int j = 0; j < 4; ++j) gll16(gA[j] + k0, lA[j]);
#pragma unroll
        for (int j = 0; j < 4; ++j) gll16(gB[j] + k0, lB[j]);
        __syncthreads();
#pragma unroll
        for (int kk = 0; kk < 2; ++kk) {
            short8 af[4], bfr[4];
#pragma unroll
            for (int mm = 0; mm < 4; ++mm) {
                const int row = wm + mm * 16 + lm;
                const int ch = (kk * 4 + quad) ^ (row & 7);
                af[mm] = *(short8*)&As[row * 64 + ch * 8];
            }
#pragma unroll
            for (int nn = 0; nn < 4; ++nn) {
                const int row = wn + nn * 16 + lm;
                const int ch = (kk * 4 + quad) ^ (row & 7);
                bfr[nn] = *(short8*)&Bs[row * 64 + ch * 8];
            }
#pragma unroll
            for (int mm = 0; mm < 4; ++mm)
#pragma unroll
                for (int nn = 0; nn < 4; ++nn)
                    acc[mm][nn] = __builtin_amdgcn_mfma_f32_16x16x32_bf16(
                        af[mm], bfr[nn], acc[mm][nn], 0, 0, 0);
        }
    }

#pragma unroll
    for (int mm = 0; mm < 4; ++mm)
#pragma unroll
        for (int nn = 0; nn < 4; ++nn)
#pragma unroll
            for (int r = 0; r < 4; ++r) {
                const int row = m0 + wm + mm * 16 + quad * 4 + r;
                const int col = n0 + wn + nn * 16 + lm;
                const float vv = acc[mm][nn][r];
                if (MODE == 0) {
                    outb[(size_t)row * ldc + col] = f2bf(vv);
                } else if (MODE == 1) {
                    outf[(size_t)row * ldc + col] =
                        vv + bias[col] + resid[(size_t)row * ldc + col];
                } else {
                    const float gv = vv + bias[col];
                    // tanh-approx GELU: x * sigmoid(2*0.79788456*(x+0.044715x^3))
                    const float u = 0.7978845608f * gv * (1.0f + 0.044715f * gv * gv);
                    const float ge = gv / (1.0f + __expf(-2.0f * u));
                    outb[(size_t)row * ldc + col] = f2bf(ge);
                }
            }
}

// ---------------------------------------------------------------------------
// MFMA causal flash attention over fused QKV buffer [ROWS][3072].
// Block = 64 q-rows x head x batch, 256 thr; wave w owns q rows w*16..+15.
// ---------------------------------------------------------------------------
__global__ __launch_bounds__(256) void attn_mfma(const short* __restrict__ qkv,
                                                 short* __restrict__ o) {
    __shared__ __align__(16) short Ks[64 * 64];     // [j][d] swizzled
    __shared__ __align__(16) short Vt[64 * 64];     // [d][j] swizzled
    __shared__ __align__(16) short Ps[4 * 16 * 64]; // per-wave [m][j] swizzled

    const int tid = threadIdx.x;
    const int qt = blockIdx.x, h = blockIdx.y, b = blockIdx.z;
    const int w = tid >> 6, lane = tid & 63;
    const int lm = lane & 15, quad = lane >> 4;

    const int sj  = tid >> 2;          // staging row 0..63
    const int sd0 = (tid & 3) * 16;    // staging d-chunk

    // Q A-frags for this wave's 16 rows, pre-scaled by 0.125 (exact pow2)
    short8 aq[2];
    {
        const short* qrow =
            qkv + (size_t)(b * SEQ + qt * 64 + w * 16 + lm) * QKV_N + h * DK;
#pragma unroll
        for (int kk = 0; kk < 2; ++kk) {
            short8 raw = *(const short8*)(qrow + kk * 32 + quad * 8);
            short8 sc;
#pragma unroll
            for (int j = 0; j < 8; ++j) sc[j] = f2bf(bf2f(raw[j]) * 0.125f);
            aq[kk] = sc;
        }
    }

    f32x4 accO[4];
#pragma unroll
    for (int i = 0; i < 4; ++i) accO[i] = (f32x4){0.f, 0.f, 0.f, 0.f};
    float mrow[4] = {-1e30f, -1e30f, -1e30f, -1e30f};
    float lrow[4] = {0.f, 0.f, 0.f, 0.f};

    short* pw = &Ps[w * 1024];

    for (int kt = 0; kt <= qt; ++kt) {
        __syncthreads();
        {
            const short* ksrc =
                qkv + (size_t)(b * SEQ + kt * 64 + sj) * QKV_N + D_MODEL + h * DK + sd0;
            short8 k0v = *(const short8*)ksrc;
            short8 k1v = *(const short8*)(ksrc + 8);
            *(short8*)&Ks[swz(sj, sd0)]     = k0v;
            *(short8*)&Ks[swz(sj, sd0 + 8)] = k1v;
            const short* vsrc =
                qkv + (size_t)(b * SEQ + kt * 64 + sj) * QKV_N + 2 * D_MODEL + h * DK + sd0;
            short8 v0v = *(const short8*)vsrc;
            short8 v1v = *(const short8*)(vsrc + 8);
#pragma unroll
            for (int dd = 0; dd < 8; ++dd) Vt[swz(sd0 + dd, sj)]     = v0v[dd];
#pragma unroll
            for (int dd = 0; dd < 8; ++dd) Vt[swz(sd0 + 8 + dd, sj)] = v1v[dd];
        }
        __syncthreads();

        f32x4 sacc[4];
#pragma unroll
        for (int nn = 0; nn < 4; ++nn) sacc[nn] = (f32x4){0.f, 0.f, 0.f, 0.f};
#pragma unroll
        for (int kk = 0; kk < 2; ++kk)
#pragma unroll
            for (int nn = 0; nn < 4; ++nn) {
                short8 bfrag = *(short8*)&Ks[swz(nn * 16 + lm, kk * 32 + quad * 8)];
                sacc[nn] = __builtin_amdgcn_mfma_f32_16x16x32_bf16(
                    aq[kk], bfrag, sacc[nn], 0, 0, 0);
            }

        if (kt == qt) {
#pragma unroll
            for (int nn = 0; nn < 4; ++nn) {
                const int kg = nn * 16 + lm;
#pragma unroll
                for (int r = 0; r < 4; ++r) {
                    const int qg = w * 16 + quad * 4 + r;
                    if (kg > qg) sacc[nn][r] = -1e30f;
                }
            }
        }

        float mnew[4], alpha[4], rsum[4];
#pragma unroll
        for (int r = 0; r < 4; ++r) {
            float mx = fmaxf(fmaxf(sacc[0][r], sacc[1][r]), fmaxf(sacc[2][r], sacc[3][r]));
#pragma unroll
            for (int msk = 1; msk <= 8; msk <<= 1) mx = fmaxf(mx, __shfl_xor(mx, msk));
            mnew[r] = fmaxf(mrow[r], mx);
            alpha[r] = __expf(mrow[r] - mnew[r]);
            rsum[r] = 0.f;
        }
#pragma unroll
        for (int nn = 0; nn < 4; ++nn)
#pragma unroll
            for (int r = 0; r < 4; ++r) {
                const float p = __expf(sacc[nn][r] - mnew[r]);
                sacc[nn][r] = p;
                rsum[r] += p;
            }
#pragma unroll
        for (int r = 0; r < 4; ++r) {
#pragma unroll
            for (int msk = 1; msk <= 8; msk <<= 1) rsum[r] += __shfl_xor(rsum[r], msk);
            lrow[r] = lrow[r] * alpha[r] + rsum[r];
            mrow[r] = mnew[r];
        }
#pragma unroll
        for (int nn = 0; nn < 4; ++nn)
#pragma unroll
            for (int r = 0; r < 4; ++r) accO[nn][r] *= alpha[r];

#pragma unroll
        for (int nn = 0; nn < 4; ++nn)
#pragma unroll
            for (int r = 0; r < 4; ++r)
                pw[swz(quad * 4 + r, nn * 16 + lm)] = f2bf(sacc[nn][r]);

#pragma unroll
        for (int kk = 0; kk < 2; ++kk) {
            short8 afrag = *(short8*)&pw[swz(lm, kk * 32 + quad * 8)];
#pragma unroll
            for (int nn = 0; nn < 4; ++nn) {
                short8 bfrag = *(short8*)&Vt[swz(nn * 16 + lm, kk * 32 + quad * 8)];
                accO[nn] = __builtin_amdgcn_mfma_f32_16x16x32_bf16(
                    afrag, bfrag, accO[nn], 0, 0, 0);
            }
        }
    }

#pragma unroll
    for (int r = 0; r < 4; ++r) {
        const float invl = 1.0f / lrow[r];
        const int row = b * SEQ + qt * 64 + w * 16 + quad * 4 + r;
#pragma unroll
        for (int nn = 0; nn < 4; ++nn)
            o[(size_t)row * D_MODEL + h * DK + nn * 16 + lm] = f2bf(accO[nn][r] * invl);
    }
}

// ---------------------------------------------------------------------------
// launcher
// ---------------------------------------------------------------------------
extern "C" void kernel_launch(void* const* d_in, const int* in_sizes, int n_in,
                              void* d_out, int out_size, void* d_ws, size_t ws_size,
                              hipStream_t stream) {
    const float* x     = (const float*)d_in[0];
    const float* ln1_g = (const float*)d_in[1];
    const float* ln1_b = (const float*)d_in[2];
    const float* w_q   = (const float*)d_in[3];
    const float* w_k   = (const float*)d_in[4];
    const float* w_v   = (const float*)d_in[5];
    const float* w_o   = (const float*)d_in[6];
    const float* b_o   = (const float*)d_in[7];
    const float* ln2_g = (const float*)d_in[8];
    const float* ln2_b = (const float*)d_in[9];
    const float* w1    = (const float*)d_in[10];
    const float* b1    = (const float*)d_in[11];
    const float* w2    = (const float*)d_in[12];
    const float* b2    = (const float*)d_in[13];
    float* out = (float*)d_out;

    char* ws = (char*)d_ws;
    size_t off = 0;
    auto alloc = [&](size_t bytes) {
        char* p = ws + off;
        off += (bytes + 255) & ~(size_t)255;
        return p;
    };
    short* h_bf   = (short*)alloc((size_t)ROWS * D_MODEL * 2);  // 16 MB
    short* qkv_bf = (short*)alloc((size_t)ROWS * QKV_N * 2);    // 48 MB
    short* a_bf   = (short*)alloc((size_t)ROWS * D_MODEL * 2);  // 16 MB (adjacent to qkv)
    float* x1     = (float*)alloc((size_t)ROWS * D_MODEL * 4);  // 32 MB
    short* wqkvT  = (short*)alloc((size_t)QKV_N * D_MODEL * 2); // 6 MB  [3072][1024]
    short* woT    = (short*)alloc((size_t)D_MODEL * D_MODEL * 2);
    short* w1T    = (short*)alloc((size_t)D_MODEL * FFN_DIM * 2);
    short* w2T    = (short*)alloc((size_t)FFN_DIM * D_MODEL * 2);
    short* g1_bf  = qkv_bf;  // [8192][4096] bf16 = 64 MB, spans qkv_bf + a_bf

    // weight convert+transpose ([K][N] fp32 -> [N][K] bf16)
    convT<<<dim3(16, 16), 256, 0, stream>>>(w_q, wqkvT, D_MODEL, D_MODEL);
    convT<<<dim3(16, 16), 256, 0, stream>>>(w_k, wqkvT + (size_t)D_MODEL * D_MODEL,
                                            D_MODEL, D_MODEL);
    convT<<<dim3(16, 16), 256, 0, stream>>>(w_v, wqkvT + (size_t)2 * D_MODEL * D_MODEL,
                                            D_MODEL, D_MODEL);
    convT<<<dim3(16, 16), 256, 0, stream>>>(w_o, woT, D_MODEL, D_MODEL);
    convT<<<dim3(64, 16), 256, 0, stream>>>(w1, w1T, D_MODEL, FFN_DIM);
    convT<<<dim3(16, 64), 256, 0, stream>>>(w2, w2T, FFN_DIM, D_MODEL);

    // LN1
    ln_kernel<<<ROWS, 256, 0, stream>>>(x, ln1_g, ln1_b, h_bf);

    // fused QKV projection: [8192][3072]
    gemm128<0><<<dim3(QKV_N / 128, ROWS / 128), 256, 0, stream>>>(
        h_bf, wqkvT, ROWS, QKV_N, D_MODEL, QKV_N,
        nullptr, nullptr, nullptr, qkv_bf);

    // attention
    attn_mfma<<<dim3(SEQ / 64, NHEAD, BATCH), 256, 0, stream>>>(qkv_bf, a_bf);

    // output projection + bias + residual -> x1 (fp32)
    gemm128<1><<<dim3(D_MODEL / 128, ROWS / 128), 256, 0, stream>>>(
        a_bf, woT, ROWS, D_MODEL, D_MODEL, D_MODEL, b_o, x, x1, nullptr);

    // LN2
    ln_kernel<<<ROWS, 256, 0, stream>>>(x1, ln2_g, ln2_b, h_bf);

    // FFN1 + tanh-GELU -> g1_bf
    gemm128<2><<<dim3(FFN_DIM / 128, ROWS / 128), 256, 0, stream>>>(
        h_bf, w1T, ROWS, FFN_DIM, D_MODEL, FFN_DIM, b1, nullptr, nullptr, g1_bf);

    // FFN2 + bias + residual -> out
    gemm128<1><<<dim3(D_MODEL / 128, ROWS / 128), 256, 0, stream>>>(
        g1_bf, w2T, ROWS, D_MODEL, FFN_DIM, D_MODEL, b2, x1, out, nullptr);
}

// Round 5
// 511.589 us; speedup vs baseline: 3.1318x; 1.0377x over previous
//
#include <hip/hip_runtime.h>
#include <hip/hip_bf16.h>
#include <math.h>

#define D_MODEL 1024
#define FFN_DIM 4096
#define NHEAD 16
#define DK 64
#define BATCH 16
#define SEQ 512
#define ROWS (BATCH * SEQ) /* 8192 */
#define QKV_N 3072

typedef short short8 __attribute__((ext_vector_type(8)));
typedef float f32x4 __attribute__((ext_vector_type(4)));

__device__ __forceinline__ float bf2f(short s) {
    return __uint_as_float(((unsigned)(unsigned short)s) << 16);
}
__device__ __forceinline__ short f2bf(float f) {
    unsigned u = __float_as_uint(f);
    u += 0x7fff + ((u >> 16) & 1);   // round-to-nearest-even
    return (short)(u >> 16);
}

// XOR-swizzled index into a [rows][64] bf16 tile (8-elem blocks kept contiguous)
__device__ __forceinline__ int swz(int row, int col) {
    int s = (row ^ (row >> 3)) & 7;
    return row * 64 + ((((col >> 3) ^ s) << 3) | (col & 7));
}

// async 16B global -> LDS (wave-uniform LDS base + lane*16)
__device__ __forceinline__ void gll16(const short* g, short* l) {
    __builtin_amdgcn_global_load_lds(
        (const __attribute__((address_space(1))) unsigned int*)g,
        (__attribute__((address_space(3))) unsigned int*)l, 16, 0, 0);
}

// ---------------------------------------------------------------------------
// fused fp32->bf16 convert + transpose: in[K][N] fp32 -> out[N][K] bf16
// ---------------------------------------------------------------------------
__global__ __launch_bounds__(256) void convT(const float* __restrict__ in,
                                             short* __restrict__ out,
                                             int K, int N) {
    __shared__ short t[64 * 64];
    const int tid = threadIdx.x;
    const int k0 = blockIdx.y * 64, n0 = blockIdx.x * 64;
    {
        const int r = tid >> 4;           // 0..15
        const int c4 = (tid & 15) * 4;    // 0..60
#pragma unroll
        for (int i = 0; i < 4; ++i) {
            const int row = i * 16 + r;   // k-local
            float4 vv = *(const float4*)&in[(size_t)(k0 + row) * N + n0 + c4];
            t[swz(row, c4 + 0)] = f2bf(vv.x);
            t[swz(row, c4 + 1)] = f2bf(vv.y);
            t[swz(row, c4 + 2)] = f2bf(vv.z);
            t[swz(row, c4 + 3)] = f2bf(vv.w);
        }
    }
    __syncthreads();
    {
        const int n = tid >> 2;           // 0..63
        const int kc = (tid & 3) * 16;
        short tmp[16];
#pragma unroll
        for (int kk = 0; kk < 16; ++kk) tmp[kk] = t[swz(kc + kk, n)];
        short8 s0, s1;
#pragma unroll
        for (int j = 0; j < 8; ++j) { s0[j] = tmp[j]; s1[j] = tmp[8 + j]; }
        short* dst = &out[(size_t)(n0 + n) * K + k0 + kc];
        *(short8*)dst = s0;
        *(short8*)(dst + 8) = s1;
    }
}

// ---------------------------------------------------------------------------
// LayerNorm over 1024 elems, one block (256 thr) per row, bf16 output
// ---------------------------------------------------------------------------
__global__ __launch_bounds__(256) void ln_kernel(const float* __restrict__ x,
                                                 const float* __restrict__ g,
                                                 const float* __restrict__ beta,
                                                 short* __restrict__ out) {
    const int row = blockIdx.x;
    const int tid = threadIdx.x;
    const float4 xv = ((const float4*)(x + (size_t)row * D_MODEL))[tid];
    float s  = xv.x + xv.y + xv.z + xv.w;
    float s2 = xv.x * xv.x + xv.y * xv.y + xv.z * xv.z + xv.w * xv.w;
#pragma unroll
    for (int off = 32; off >= 1; off >>= 1) {
        s  += __shfl_down(s, off);
        s2 += __shfl_down(s2, off);
    }
    __shared__ float red[8];
    if ((tid & 63) == 0) { red[(tid >> 6) * 2] = s; red[(tid >> 6) * 2 + 1] = s2; }
    __syncthreads();
    s  = red[0] + red[2] + red[4] + red[6];
    s2 = red[1] + red[3] + red[5] + red[7];
    const float mu  = s * (1.0f / D_MODEL);
    const float var = s2 * (1.0f / D_MODEL) - mu * mu;
    const float r   = rsqrtf(var + 1e-5f);
    const int c = tid * 4;
    short4 ov;
    ov.x = f2bf((xv.x - mu) * r * g[c + 0] + beta[c + 0]);
    ov.y = f2bf((xv.y - mu) * r * g[c + 1] + beta[c + 1]);
    ov.z = f2bf((xv.z - mu) * r * g[c + 2] + beta[c + 2]);
    ov.w = f2bf((xv.w - mu) * r * g[c + 3] + beta[c + 3]);
    *(short4*)(out + (size_t)row * D_MODEL + c) = ov;
}

// ---------------------------------------------------------------------------
// bf16 MFMA GEMM: C[M,N] = A[M,K] @ Bt[N,K]^T. 128x128 tile, 4 waves, BK=64,
// XOR-swizzled LDS chunks, double-buffered LDS with global_load_lds prefetch
// (loads for k0+64 issued after the barrier, overlapping compute on k0).
// MODE 0: out bf16; MODE 1: fp32 = acc+bias+resid; MODE 2: bf16 = gelu_tanh(acc+bias)
// ---------------------------------------------------------------------------
template <int MODE>
__global__ __launch_bounds__(256) void gemm128(
    const short* __restrict__ A, const short* __restrict__ Bt,
    int M, int N, int K, int ldc,
    const float* __restrict__ bias, const float* __restrict__ resid,
    float* __restrict__ outf, short* __restrict__ outb) {
    __shared__ __align__(16) short As[2][128 * 64];
    __shared__ __align__(16) short Bs[2][128 * 64];
    const int tid = threadIdx.x;
    const int w = tid >> 6, lane = tid & 63;
    const int lm = lane & 15, quad = lane >> 4;
    const int m0 = blockIdx.y * 128, n0 = blockIdx.x * 128;
    const int wm = (w & 1) * 64, wn = (w >> 1) * 64;

    // staging: call j covers rows j*32 + w*8 .. +7; lane -> (row=lane>>3,
    // lds chunk = lane&7). Global k-chunk XOR-permuted so LDS dest stays
    // lane-contiguous while storage is swizzled.
    const int srl = lane >> 3;
    const int gch = (lane & 7) ^ srl;
    const short* gA[4];
    const short* gB[4];
    int lofs[4];
#pragma unroll
    for (int j = 0; j < 4; ++j) {
        const int row = j * 32 + w * 8 + srl;
        gA[j] = A  + (size_t)(m0 + row) * K + gch * 8;
        gB[j] = Bt + (size_t)(n0 + row) * K + gch * 8;
        lofs[j] = (j * 32 + w * 8) * 64;
    }

    f32x4 acc[4][4];
#pragma unroll
    for (int i = 0; i < 4; ++i)
#pragma unroll
        for (int j = 0; j < 4; ++j) acc[i][j] = (f32x4){0.f, 0.f, 0.f, 0.f};

    // prologue: stage k0=0 into buffer 0
#pragma unroll
    for (int j = 0; j < 4; ++j) gll16(gA[j], &As[0][lofs[j]]);
#pragma unroll
    for (int j = 0; j < 4; ++j) gll16(gB[j], &Bs[0][lofs[j]]);

    int buf = 0;
    for (int k0 = 0; k0 < K; k0 += 64) {
        __syncthreads();   // drains vmcnt -> buf ready; prev readers of buf^1 done
        if (k0 + 64 < K) {
#pragma unroll
            for (int j = 0; j < 4; ++j) gll16(gA[j] + k0 + 64, &As[buf ^ 1][lofs[j]]);
#pragma unroll
            for (int j = 0; j < 4; ++j) gll16(gB[j] + k0 + 64, &Bs[buf ^ 1][lofs[j]]);
        }
#pragma unroll
        for (int kk = 0; kk < 2; ++kk) {
            short8 af[4], bfr[4];
#pragma unroll
            for (int mm = 0; mm < 4; ++mm) {
                const int row = wm + mm * 16 + lm;
                const int ch = (kk * 4 + quad) ^ (row & 7);
                af[mm] = *(short8*)&As[buf][row * 64 + ch * 8];
            }
#pragma unroll
            for (int nn = 0; nn < 4; ++nn) {
                const int row = wn + nn * 16 + lm;
                const int ch = (kk * 4 + quad) ^ (row & 7);
                bfr[nn] = *(short8*)&Bs[buf][row * 64 + ch * 8];
            }
#pragma unroll
            for (int mm = 0; mm < 4; ++mm)
#pragma unroll
                for (int nn = 0; nn < 4; ++nn)
                    acc[mm][nn] = __builtin_amdgcn_mfma_f32_16x16x32_bf16(
                        af[mm], bfr[nn], acc[mm][nn], 0, 0, 0);
        }
        buf ^= 1;
    }

#pragma unroll
    for (int mm = 0; mm < 4; ++mm)
#pragma unroll
        for (int nn = 0; nn < 4; ++nn)
#pragma unroll
            for (int r = 0; r < 4; ++r) {
                const int row = m0 + wm + mm * 16 + quad * 4 + r;
                const int col = n0 + wn + nn * 16 + lm;
                const float vv = acc[mm][nn][r];
                if (MODE == 0) {
                    outb[(size_t)row * ldc + col] = f2bf(vv);
                } else if (MODE == 1) {
                    outf[(size_t)row * ldc + col] =
                        vv + bias[col] + resid[(size_t)row * ldc + col];
                } else {
                    const float gv = vv + bias[col];
                    const float u = 0.7978845608f * gv * (1.0f + 0.044715f * gv * gv);
                    const float ge = gv / (1.0f + __expf(-2.0f * u));
                    outb[(size_t)row * ldc + col] = f2bf(ge);
                }
            }
}

// ---------------------------------------------------------------------------
// MFMA causal flash attention over fused QKV buffer [ROWS][3072].
// Block = 128 q-rows x head x batch, 256 thr; wave w owns q rows w*32..+31
// as two 16-row m-frags. K/V staged once per 64-col k-tile serves all 128 rows.
// ---------------------------------------------------------------------------
__global__ __launch_bounds__(256) void attn_mfma(const short* __restrict__ qkv,
                                                 short* __restrict__ o) {
    __shared__ __align__(16) short Ks[64 * 64];     // [j][d] swizzled
    __shared__ __align__(16) short Vt[64 * 64];     // [d][j] swizzled
    __shared__ __align__(16) short Ps[4][32 * 64];  // per-wave [m][j] swizzled

    const int tid = threadIdx.x;
    const int qt = blockIdx.x, h = blockIdx.y, b = blockIdx.z;
    const int w = tid >> 6, lane = tid & 63;
    const int lm = lane & 15, quad = lane >> 4;

    const int sj  = tid >> 2;          // staging row 0..63
    const int sd0 = (tid & 3) * 16;    // staging d-chunk

    // Q A-frags for this wave's 2 m-frags, pre-scaled by 0.125 (exact pow2)
    short8 aq[2][2];
#pragma unroll
    for (int m = 0; m < 2; ++m) {
        const short* qrow =
            qkv + (size_t)(b * SEQ + qt * 128 + w * 32 + m * 16 + lm) * QKV_N + h * DK;
#pragma unroll
        for (int kk = 0; kk < 2; ++kk) {
            short8 raw = *(const short8*)(qrow + kk * 32 + quad * 8);
            short8 sc;
#pragma unroll
            for (int j = 0; j < 8; ++j) sc[j] = f2bf(bf2f(raw[j]) * 0.125f);
            aq[m][kk] = sc;
        }
    }

    f32x4 accO[2][4];
#pragma unroll
    for (int m = 0; m < 2; ++m)
#pragma unroll
        for (int i = 0; i < 4; ++i) accO[m][i] = (f32x4){0.f, 0.f, 0.f, 0.f};
    float mrow[2][4], lrow[2][4];
#pragma unroll
    for (int m = 0; m < 2; ++m)
#pragma unroll
        for (int r = 0; r < 4; ++r) { mrow[m][r] = -1e30f; lrow[m][r] = 0.f; }

    short* pw = Ps[w];
    const int ktmax = 2 * qt + 1;

    for (int kt = 0; kt <= ktmax; ++kt) {
        __syncthreads();
        {
            const short* ksrc =
                qkv + (size_t)(b * SEQ + kt * 64 + sj) * QKV_N + D_MODEL + h * DK + sd0;
            short8 k0v = *(const short8*)ksrc;
            short8 k1v = *(const short8*)(ksrc + 8);
            *(short8*)&Ks[swz(sj, sd0)]     = k0v;
            *(short8*)&Ks[swz(sj, sd0 + 8)] = k1v;
            const short* vsrc =
                qkv + (size_t)(b * SEQ + kt * 64 + sj) * QKV_N + 2 * D_MODEL + h * DK + sd0;
            short8 v0v = *(const short8*)vsrc;
            short8 v1v = *(const short8*)(vsrc + 8);
#pragma unroll
            for (int dd = 0; dd < 8; ++dd) Vt[swz(sd0 + dd, sj)]     = v0v[dd];
#pragma unroll
            for (int dd = 0; dd < 8; ++dd) Vt[swz(sd0 + 8 + dd, sj)] = v1v[dd];
        }
        __syncthreads();

        bool live[2];
#pragma unroll
        for (int m = 0; m < 2; ++m) {
            const int rowmin = qt * 128 + w * 32 + m * 16;
            live[m] = (kt * 64 <= rowmin + 15);   // tile not fully masked
            if (!live[m]) continue;
            const bool needmask = (kt * 64 + 63 > rowmin);

            f32x4 sacc[4];
#pragma unroll
            for (int nn = 0; nn < 4; ++nn) sacc[nn] = (f32x4){0.f, 0.f, 0.f, 0.f};
#pragma unroll
            for (int kk = 0; kk < 2; ++kk)
#pragma unroll
                for (int nn = 0; nn < 4; ++nn) {
                    short8 bfrag = *(short8*)&Ks[swz(nn * 16 + lm, kk * 32 + quad * 8)];
                    sacc[nn] = __builtin_amdgcn_mfma_f32_16x16x32_bf16(
                        aq[m][kk], bfrag, sacc[nn], 0, 0, 0);
                }

            if (needmask) {
#pragma unroll
                for (int nn = 0; nn < 4; ++nn) {
                    const int kg = kt * 64 + nn * 16 + lm;
#pragma unroll
                    for (int r = 0; r < 4; ++r) {
                        const int qg = rowmin + quad * 4 + r;
                        if (kg > qg) sacc[nn][r] = -1e30f;
                    }
                }
            }

            float mnew[4], alpha[4], rsum[4];
#pragma unroll
            for (int r = 0; r < 4; ++r) {
                float mx = fmaxf(fmaxf(sacc[0][r], sacc[1][r]),
                                 fmaxf(sacc[2][r], sacc[3][r]));
#pragma unroll
                for (int msk = 1; msk <= 8; msk <<= 1) mx = fmaxf(mx, __shfl_xor(mx, msk));
                mnew[r] = fmaxf(mrow[m][r], mx);
                alpha[r] = __expf(mrow[m][r] - mnew[r]);
                rsum[r] = 0.f;
            }
#pragma unroll
            for (int nn = 0; nn < 4; ++nn)
#pragma unroll
                for (int r = 0; r < 4; ++r) {
                    const float p = __expf(sacc[nn][r] - mnew[r]);
                    sacc[nn][r] = p;
                    rsum[r] += p;
                }
#pragma unroll
            for (int r = 0; r < 4; ++r) {
#pragma unroll
                for (int msk = 1; msk <= 8; msk <<= 1) rsum[r] += __shfl_xor(rsum[r], msk);
                lrow[m][r] = lrow[m][r] * alpha[r] + rsum[r];
                mrow[m][r] = mnew[r];
            }
#pragma unroll
            for (int nn = 0; nn < 4; ++nn)
#pragma unroll
                for (int r = 0; r < 4; ++r) accO[m][nn][r] *= alpha[r];

#pragma unroll
            for (int nn = 0; nn < 4; ++nn)
#pragma unroll
                for (int r = 0; r < 4; ++r)
                    pw[swz(m * 16 + quad * 4 + r, nn * 16 + lm)] = f2bf(sacc[nn][r]);
        }

        // O += P V (B-frags shared across both m-frags)
#pragma unroll
        for (int kk = 0; kk < 2; ++kk) {
            short8 bfr[4];
#pragma unroll
            for (int nn = 0; nn < 4; ++nn)
                bfr[nn] = *(short8*)&Vt[swz(nn * 16 + lm, kk * 32 + quad * 8)];
#pragma unroll
            for (int m = 0; m < 2; ++m) {
                if (!live[m]) continue;
                short8 afrag = *(short8*)&pw[swz(m * 16 + lm, kk * 32 + quad * 8)];
#pragma unroll
                for (int nn = 0; nn < 4; ++nn)
                    accO[m][nn] = __builtin_amdgcn_mfma_f32_16x16x32_bf16(
                        afrag, bfr[nn], accO[m][nn], 0, 0, 0);
            }
        }
    }

#pragma unroll
    for (int m = 0; m < 2; ++m)
#pragma unroll
        for (int r = 0; r < 4; ++r) {
            const float invl = 1.0f / lrow[m][r];
            const int row = b * SEQ + qt * 128 + w * 32 + m * 16 + quad * 4 + r;
#pragma unroll
            for (int nn = 0; nn < 4; ++nn)
                o[(size_t)row * D_MODEL + h * DK + nn * 16 + lm] =
                    f2bf(accO[m][nn][r] * invl);
        }
}

// ---------------------------------------------------------------------------
// launcher
// ---------------------------------------------------------------------------
extern "C" void kernel_launch(void* const* d_in, const int* in_sizes, int n_in,
                              void* d_out, int out_size, void* d_ws, size_t ws_size,
                              hipStream_t stream) {
    const float* x     = (const float*)d_in[0];
    const float* ln1_g = (const float*)d_in[1];
    const float* ln1_b = (const float*)d_in[2];
    const float* w_q   = (const float*)d_in[3];
    const float* w_k   = (const float*)d_in[4];
    const float* w_v   = (const float*)d_in[5];
    const float* w_o   = (const float*)d_in[6];
    const float* b_o   = (const float*)d_in[7];
    const float* ln2_g = (const float*)d_in[8];
    const float* ln2_b = (const float*)d_in[9];
    const float* w1    = (const float*)d_in[10];
    const float* b1    = (const float*)d_in[11];
    const float* w2    = (const float*)d_in[12];
    const float* b2    = (const float*)d_in[13];
    float* out = (float*)d_out;

    char* ws = (char*)d_ws;
    size_t off = 0;
    auto alloc = [&](size_t bytes) {
        char* p = ws + off;
        off += (bytes + 255) & ~(size_t)255;
        return p;
    };
    short* h_bf   = (short*)alloc((size_t)ROWS * D_MODEL * 2);  // 16 MB
    short* qkv_bf = (short*)alloc((size_t)ROWS * QKV_N * 2);    // 48 MB
    short* a_bf   = (short*)alloc((size_t)ROWS * D_MODEL * 2);  // 16 MB (adjacent to qkv)
    float* x1     = (float*)alloc((size_t)ROWS * D_MODEL * 4);  // 32 MB
    short* wqkvT  = (short*)alloc((size_t)QKV_N * D_MODEL * 2); // 6 MB  [3072][1024]
    short* woT    = (short*)alloc((size_t)D_MODEL * D_MODEL * 2);
    short* w1T    = (short*)alloc((size_t)D_MODEL * FFN_DIM * 2);
    short* w2T    = (short*)alloc((size_t)FFN_DIM * D_MODEL * 2);
    short* g1_bf  = qkv_bf;  // [8192][4096] bf16 = 64 MB, spans qkv_bf + a_bf

    // weight convert+transpose ([K][N] fp32 -> [N][K] bf16)
    convT<<<dim3(16, 16), 256, 0, stream>>>(w_q, wqkvT, D_MODEL, D_MODEL);
    convT<<<dim3(16, 16), 256, 0, stream>>>(w_k, wqkvT + (size_t)D_MODEL * D_MODEL,
                                            D_MODEL, D_MODEL);
    convT<<<dim3(16, 16), 256, 0, stream>>>(w_v, wqkvT + (size_t)2 * D_MODEL * D_MODEL,
                                            D_MODEL, D_MODEL);
    convT<<<dim3(16, 16), 256, 0, stream>>>(w_o, woT, D_MODEL, D_MODEL);
    convT<<<dim3(64, 16), 256, 0, stream>>>(w1, w1T, D_MODEL, FFN_DIM);
    convT<<<dim3(16, 64), 256, 0, stream>>>(w2, w2T, FFN_DIM, D_MODEL);

    // LN1
    ln_kernel<<<ROWS, 256, 0, stream>>>(x, ln1_g, ln1_b, h_bf);

    // fused QKV projection: [8192][3072]
    gemm128<0><<<dim3(QKV_N / 128, ROWS / 128), 256, 0, stream>>>(
        h_bf, wqkvT, ROWS, QKV_N, D_MODEL, QKV_N,
        nullptr, nullptr, nullptr, qkv_bf);

    // attention (128 q-rows per block)
    attn_mfma<<<dim3(SEQ / 128, NHEAD, BATCH), 256, 0, stream>>>(qkv_bf, a_bf);

    // output projection + bias + residual -> x1 (fp32)
    gemm128<1><<<dim3(D_MODEL / 128, ROWS / 128), 256, 0, stream>>>(
        a_bf, woT, ROWS, D_MODEL, D_MODEL, D_MODEL, b_o, x, x1, nullptr);

    // LN2
    ln_kernel<<<ROWS, 256, 0, stream>>>(x1, ln2_g, ln2_b, h_bf);

    // FFN1 + tanh-GELU -> g1_bf
    gemm128<2><<<dim3(FFN_DIM / 128, ROWS / 128), 256, 0, stream>>>(
        h_bf, w1T, ROWS, FFN_DIM, D_MODEL, FFN_DIM, b1, nullptr, nullptr, g1_bf);

    // FFN2 + bias + residual -> out
    gemm128<1><<<dim3(D_MODEL / 128, ROWS / 128), 256, 0, stream>>>(
        g1_bf, w2T, ROWS, D_MODEL, FFN_DIM, D_MODEL, b2, x1, out, nullptr);
}

// Round 6
// 504.541 us; speedup vs baseline: 3.1755x; 1.0140x over previous
//
#include <hip/hip_runtime.h>
#include <hip/hip_bf16.h>
#include <math.h>

#define D_MODEL 1024
#define FFN_DIM 4096
#define NHEAD 16
#define DK 64
#define BATCH 16
#define SEQ 512
#define ROWS (BATCH * SEQ) /* 8192 */
#define QKV_N 3072

typedef short short8 __attribute__((ext_vector_type(8)));
typedef float f32x4 __attribute__((ext_vector_type(4)));

__device__ __forceinline__ float bf2f(short s) {
    return __uint_as_float(((unsigned)(unsigned short)s) << 16);
}
__device__ __forceinline__ short f2bf(float f) {
    unsigned u = __float_as_uint(f);
    u += 0x7fff + ((u >> 16) & 1);   // round-to-nearest-even
    return (short)(u >> 16);
}

// XOR-swizzled index into a [rows][64] bf16 tile (8-elem blocks kept contiguous)
__device__ __forceinline__ int swz(int row, int col) {
    int s = (row ^ (row >> 3)) & 7;
    return row * 64 + ((((col >> 3) ^ s) << 3) | (col & 7));
}

// async 16B global -> LDS (wave-uniform LDS base + lane*16)
__device__ __forceinline__ void gll16(const short* g, short* l) {
    __builtin_amdgcn_global_load_lds(
        (const __attribute__((address_space(1))) unsigned int*)g,
        (__attribute__((address_space(3))) unsigned int*)l, 16, 0, 0);
}

// ---------------------------------------------------------------------------
// Weight preshuffle: W[K][N] fp32 -> frag-major bf16.
// Frag f = (n/16)*(K/32) + (k/32); within frag, lane = (klocal/8)*16 + n%16
// holds 8 consecutive k elems. B-frag load in GEMM = one coalesced 1KB read.
// grid = (N/16, K/128), 256 thr (4 frags per block).
// ---------------------------------------------------------------------------
__global__ __launch_bounds__(256) void convShuf(const float* __restrict__ in,
                                                short* __restrict__ out,
                                                int K, int N) {
    const int tid = threadIdx.x;
    const int lane = tid & 63, fl = tid >> 6;
    const int lm = lane & 15, quad = lane >> 4;
    const int nt = blockIdx.x;
    const int kc = blockIdx.y * 4 + fl;
    const int n = nt * 16 + lm;
    const int kb = kc * 32 + quad * 8;
    short8 v;
#pragma unroll
    for (int j = 0; j < 8; ++j) v[j] = f2bf(in[(size_t)(kb + j) * N + n]);
    *(short8*)&out[((size_t)nt * (K / 32) + kc) * 512 + lane * 8] = v;
}

// ---------------------------------------------------------------------------
// LayerNorm over 1024 elems, one block (256 thr) per row, bf16 output
// ---------------------------------------------------------------------------
__global__ __launch_bounds__(256) void ln_kernel(const float* __restrict__ x,
                                                 const float* __restrict__ g,
                                                 const float* __restrict__ beta,
                                                 short* __restrict__ out) {
    const int row = blockIdx.x;
    const int tid = threadIdx.x;
    const float4 xv = ((const float4*)(x + (size_t)row * D_MODEL))[tid];
    float s  = xv.x + xv.y + xv.z + xv.w;
    float s2 = xv.x * xv.x + xv.y * xv.y + xv.z * xv.z + xv.w * xv.w;
#pragma unroll
    for (int off = 32; off >= 1; off >>= 1) {
        s  += __shfl_down(s, off);
        s2 += __shfl_down(s2, off);
    }
    __shared__ float red[8];
    if ((tid & 63) == 0) { red[(tid >> 6) * 2] = s; red[(tid >> 6) * 2 + 1] = s2; }
    __syncthreads();
    s  = red[0] + red[2] + red[4] + red[6];
    s2 = red[1] + red[3] + red[5] + red[7];
    const float mu  = s * (1.0f / D_MODEL);
    const float var = s2 * (1.0f / D_MODEL) - mu * mu;
    const float r   = rsqrtf(var + 1e-5f);
    const int c = tid * 4;
    short4 ov;
    ov.x = f2bf((xv.x - mu) * r * g[c + 0] + beta[c + 0]);
    ov.y = f2bf((xv.y - mu) * r * g[c + 1] + beta[c + 1]);
    ov.z = f2bf((xv.z - mu) * r * g[c + 2] + beta[c + 2]);
    ov.w = f2bf((xv.w - mu) * r * g[c + 3] + beta[c + 3]);
    *(short4*)(out + (size_t)row * D_MODEL + c) = ov;
}

// ---------------------------------------------------------------------------
// bf16 MFMA GEMM, B from preshuffled frag-major global (never in LDS):
// C[M,N] = A[M,K] @ W. 128x128 tile, 4 waves (2x2), BK=64.
// A: XOR-swizzled LDS, double-buffered, global_load_lds width-16 staging.
// B: direct global_load_dwordx4 per frag (coalesced 1KB, L1/L2-hot).
// MODE 0: out bf16; MODE 1: fp32 = acc+bias+resid; MODE 2: bf16 = gelu_tanh(acc+bias)
// ---------------------------------------------------------------------------
template <int MODE>
__global__ __launch_bounds__(256) void gemm128(
    const short* __restrict__ A, const short* __restrict__ Bp,
    int M, int N, int K, int ldc,
    const float* __restrict__ bias, const float* __restrict__ resid,
    float* __restrict__ outf, short* __restrict__ outb) {
    __shared__ __align__(16) short As[2][128 * 64];
    const int tid = threadIdx.x;
    const int w = tid >> 6, lane = tid & 63;
    const int lm = lane & 15, quad = lane >> 4;
    const int m0 = blockIdx.y * 128, n0 = blockIdx.x * 128;
    const int wm = (w & 1) * 64, wn = (w >> 1) * 64;
    const int KC = K / 32;

    // A staging: call j covers rows j*32 + w*8 .. +7; lane -> (row=lane>>3,
    // lds chunk = lane&7); global k-chunk XOR-permuted to match swizzle.
    const int srl = lane >> 3;
    const int gch = (lane & 7) ^ srl;
    const short* gA[4];
    int lofs[4];
#pragma unroll
    for (int j = 0; j < 4; ++j) {
        const int row = j * 32 + w * 8 + srl;
        gA[j] = A + (size_t)(m0 + row) * K + gch * 8;
        lofs[j] = (j * 32 + w * 8) * 64;
    }

    // B frag pointers: frag (nt, kc) at Bp + (nt*KC + kc)*512 + lane*8
    const short* bptr[4];
#pragma unroll
    for (int nn = 0; nn < 4; ++nn)
        bptr[nn] = Bp + ((size_t)((n0 + wn) / 16 + nn) * KC) * 512 + lane * 8;

    f32x4 acc[4][4];
#pragma unroll
    for (int i = 0; i < 4; ++i)
#pragma unroll
        for (int j = 0; j < 4; ++j) acc[i][j] = (f32x4){0.f, 0.f, 0.f, 0.f};

    // prologue: stage k0=0 into buffer 0
#pragma unroll
    for (int j = 0; j < 4; ++j) gll16(gA[j], &As[0][lofs[j]]);

    int buf = 0;
    for (int k0 = 0; k0 < K; k0 += 64) {
        __syncthreads();   // drains vmcnt -> buf ready
        if (k0 + 64 < K) {
#pragma unroll
            for (int j = 0; j < 4; ++j) gll16(gA[j] + k0 + 64, &As[buf ^ 1][lofs[j]]);
        }
#pragma unroll
        for (int kk = 0; kk < 2; ++kk) {
            const int kc = (k0 >> 5) + kk;
            short8 af[4], bfr[4];
#pragma unroll
            for (int nn = 0; nn < 4; ++nn)
                bfr[nn] = *(const short8*)(bptr[nn] + (size_t)kc * 512);
#pragma unroll
            for (int mm = 0; mm < 4; ++mm) {
                const int row = wm + mm * 16 + lm;
                const int ch = (kk * 4 + quad) ^ (row & 7);
                af[mm] = *(short8*)&As[buf][row * 64 + ch * 8];
            }
#pragma unroll
            for (int mm = 0; mm < 4; ++mm)
#pragma unroll
                for (int nn = 0; nn < 4; ++nn)
                    acc[mm][nn] = __builtin_amdgcn_mfma_f32_16x16x32_bf16(
                        af[mm], bfr[nn], acc[mm][nn], 0, 0, 0);
        }
        buf ^= 1;
    }

#pragma unroll
    for (int mm = 0; mm < 4; ++mm)
#pragma unroll
        for (int nn = 0; nn < 4; ++nn)
#pragma unroll
            for (int r = 0; r < 4; ++r) {
                const int row = m0 + wm + mm * 16 + quad * 4 + r;
                const int col = n0 + wn + nn * 16 + lm;
                const float vv = acc[mm][nn][r];
                if (MODE == 0) {
                    outb[(size_t)row * ldc + col] = f2bf(vv);
                } else if (MODE == 1) {
                    outf[(size_t)row * ldc + col] =
                        vv + bias[col] + resid[(size_t)row * ldc + col];
                } else {
                    const float gv = vv + bias[col];
                    const float u = 0.7978845608f * gv * (1.0f + 0.044715f * gv * gv);
                    const float ge = gv / (1.0f + __expf(-2.0f * u));
                    outb[(size_t)row * ldc + col] = f2bf(ge);
                }
            }
}

// ---------------------------------------------------------------------------
// MFMA causal flash attention over fused QKV buffer [ROWS][3072].
// Block = 128 q-rows x head x batch, 256 thr; wave w owns q rows w*32..+31.
// ---------------------------------------------------------------------------
__global__ __launch_bounds__(256) void attn_mfma(const short* __restrict__ qkv,
                                                 short* __restrict__ o) {
    __shared__ __align__(16) short Ks[64 * 64];     // [j][d] swizzled
    __shared__ __align__(16) short Vt[64 * 64];     // [d][j] swizzled
    __shared__ __align__(16) short Ps[4][32 * 64];  // per-wave [m][j] swizzled

    const int tid = threadIdx.x;
    const int qt = blockIdx.x, h = blockIdx.y, b = blockIdx.z;
    const int w = tid >> 6, lane = tid & 63;
    const int lm = lane & 15, quad = lane >> 4;

    const int sj  = tid >> 2;          // staging row 0..63
    const int sd0 = (tid & 3) * 16;    // staging d-chunk

    short8 aq[2][2];
#pragma unroll
    for (int m = 0; m < 2; ++m) {
        const short* qrow =
            qkv + (size_t)(b * SEQ + qt * 128 + w * 32 + m * 16 + lm) * QKV_N + h * DK;
#pragma unroll
        for (int kk = 0; kk < 2; ++kk) {
            short8 raw = *(const short8*)(qrow + kk * 32 + quad * 8);
            short8 sc;
#pragma unroll
            for (int j = 0; j < 8; ++j) sc[j] = f2bf(bf2f(raw[j]) * 0.125f);
            aq[m][kk] = sc;
        }
    }

    f32x4 accO[2][4];
#pragma unroll
    for (int m = 0; m < 2; ++m)
#pragma unroll
        for (int i = 0; i < 4; ++i) accO[m][i] = (f32x4){0.f, 0.f, 0.f, 0.f};
    float mrow[2][4], lrow[2][4];
#pragma unroll
    for (int m = 0; m < 2; ++m)
#pragma unroll
        for (int r = 0; r < 4; ++r) { mrow[m][r] = -1e30f; lrow[m][r] = 0.f; }

    short* pw = Ps[w];
    const int ktmax = 2 * qt + 1;

    for (int kt = 0; kt <= ktmax; ++kt) {
        __syncthreads();
        {
            const short* ksrc =
                qkv + (size_t)(b * SEQ + kt * 64 + sj) * QKV_N + D_MODEL + h * DK + sd0;
            short8 k0v = *(const short8*)ksrc;
            short8 k1v = *(const short8*)(ksrc + 8);
            *(short8*)&Ks[swz(sj, sd0)]     = k0v;
            *(short8*)&Ks[swz(sj, sd0 + 8)] = k1v;
            const short* vsrc =
                qkv + (size_t)(b * SEQ + kt * 64 + sj) * QKV_N + 2 * D_MODEL + h * DK + sd0;
            short8 v0v = *(const short8*)vsrc;
            short8 v1v = *(const short8*)(vsrc + 8);
#pragma unroll
            for (int dd = 0; dd < 8; ++dd) Vt[swz(sd0 + dd, sj)]     = v0v[dd];
#pragma unroll
            for (int dd = 0; dd < 8; ++dd) Vt[swz(sd0 + 8 + dd, sj)] = v1v[dd];
        }
        __syncthreads();

        bool live[2];
#pragma unroll
        for (int m = 0; m < 2; ++m) {
            const int rowmin = qt * 128 + w * 32 + m * 16;
            live[m] = (kt * 64 <= rowmin + 15);
            if (!live[m]) continue;
            const bool needmask = (kt * 64 + 63 > rowmin);

            f32x4 sacc[4];
#pragma unroll
            for (int nn = 0; nn < 4; ++nn) sacc[nn] = (f32x4){0.f, 0.f, 0.f, 0.f};
#pragma unroll
            for (int kk = 0; kk < 2; ++kk)
#pragma unroll
                for (int nn = 0; nn < 4; ++nn) {
                    short8 bfrag = *(short8*)&Ks[swz(nn * 16 + lm, kk * 32 + quad * 8)];
                    sacc[nn] = __builtin_amdgcn_mfma_f32_16x16x32_bf16(
                        aq[m][kk], bfrag, sacc[nn], 0, 0, 0);
                }

            if (needmask) {
#pragma unroll
                for (int nn = 0; nn < 4; ++nn) {
                    const int kg = kt * 64 + nn * 16 + lm;
#pragma unroll
                    for (int r = 0; r < 4; ++r) {
                        const int qg = rowmin + quad * 4 + r;
                        if (kg > qg) sacc[nn][r] = -1e30f;
                    }
                }
            }

            float mnew[4], alpha[4], rsum[4];
#pragma unroll
            for (int r = 0; r < 4; ++r) {
                float mx = fmaxf(fmaxf(sacc[0][r], sacc[1][r]),
                                 fmaxf(sacc[2][r], sacc[3][r]));
#pragma unroll
                for (int msk = 1; msk <= 8; msk <<= 1) mx = fmaxf(mx, __shfl_xor(mx, msk));
                mnew[r] = fmaxf(mrow[m][r], mx);
                alpha[r] = __expf(mrow[m][r] - mnew[r]);
                rsum[r] = 0.f;
            }
#pragma unroll
            for (int nn = 0; nn < 4; ++nn)
#pragma unroll
                for (int r = 0; r < 4; ++r) {
                    const float p = __expf(sacc[nn][r] - mnew[r]);
                    sacc[nn][r] = p;
                    rsum[r] += p;
                }
#pragma unroll
            for (int r = 0; r < 4; ++r) {
#pragma unroll
                for (int msk = 1; msk <= 8; msk <<= 1) rsum[r] += __shfl_xor(rsum[r], msk);
                lrow[m][r] = lrow[m][r] * alpha[r] + rsum[r];
                mrow[m][r] = mnew[r];
            }
#pragma unroll
            for (int nn = 0; nn < 4; ++nn)
#pragma unroll
                for (int r = 0; r < 4; ++r) accO[m][nn][r] *= alpha[r];

#pragma unroll
            for (int nn = 0; nn < 4; ++nn)
#pragma unroll
                for (int r = 0; r < 4; ++r)
                    pw[swz(m * 16 + quad * 4 + r, nn * 16 + lm)] = f2bf(sacc[nn][r]);
        }

#pragma unroll
        for (int kk = 0; kk < 2; ++kk) {
            short8 bfr[4];
#pragma unroll
            for (int nn = 0; nn < 4; ++nn)
                bfr[nn] = *(short8*)&Vt[swz(nn * 16 + lm, kk * 32 + quad * 8)];
#pragma unroll
            for (int m = 0; m < 2; ++m) {
                if (!live[m]) continue;
                short8 afrag = *(short8*)&pw[swz(m * 16 + lm, kk * 32 + quad * 8)];
#pragma unroll
                for (int nn = 0; nn < 4; ++nn)
                    accO[m][nn] = __builtin_amdgcn_mfma_f32_16x16x32_bf16(
                        afrag, bfr[nn], accO[m][nn], 0, 0, 0);
            }
        }
    }

#pragma unroll
    for (int m = 0; m < 2; ++m)
#pragma unroll
        for (int r = 0; r < 4; ++r) {
            const float invl = 1.0f / lrow[m][r];
            const int row = b * SEQ + qt * 128 + w * 32 + m * 16 + quad * 4 + r;
#pragma unroll
            for (int nn = 0; nn < 4; ++nn)
                o[(size_t)row * D_MODEL + h * DK + nn * 16 + lm] =
                    f2bf(accO[m][nn][r] * invl);
        }
}

// ---------------------------------------------------------------------------
// launcher
// ---------------------------------------------------------------------------
extern "C" void kernel_launch(void* const* d_in, const int* in_sizes, int n_in,
                              void* d_out, int out_size, void* d_ws, size_t ws_size,
                              hipStream_t stream) {
    const float* x     = (const float*)d_in[0];
    const float* ln1_g = (const float*)d_in[1];
    const float* ln1_b = (const float*)d_in[2];
    const float* w_q   = (const float*)d_in[3];
    const float* w_k   = (const float*)d_in[4];
    const float* w_v   = (const float*)d_in[5];
    const float* w_o   = (const float*)d_in[6];
    const float* b_o   = (const float*)d_in[7];
    const float* ln2_g = (const float*)d_in[8];
    const float* ln2_b = (const float*)d_in[9];
    const float* w1    = (const float*)d_in[10];
    const float* b1    = (const float*)d_in[11];
    const float* w2    = (const float*)d_in[12];
    const float* b2    = (const float*)d_in[13];
    float* out = (float*)d_out;

    char* ws = (char*)d_ws;
    size_t off = 0;
    auto alloc = [&](size_t bytes) {
        char* p = ws + off;
        off += (bytes + 255) & ~(size_t)255;
        return p;
    };
    short* h_bf   = (short*)alloc((size_t)ROWS * D_MODEL * 2);  // 16 MB
    short* qkv_bf = (short*)alloc((size_t)ROWS * QKV_N * 2);    // 48 MB
    short* a_bf   = (short*)alloc((size_t)ROWS * D_MODEL * 2);  // 16 MB (adjacent to qkv)
    float* x1     = (float*)alloc((size_t)ROWS * D_MODEL * 4);  // 32 MB
    short* wqkvP  = (short*)alloc((size_t)QKV_N * D_MODEL * 2); // preshuffled
    short* woP    = (short*)alloc((size_t)D_MODEL * D_MODEL * 2);
    short* w1P    = (short*)alloc((size_t)D_MODEL * FFN_DIM * 2);
    short* w2P    = (short*)alloc((size_t)FFN_DIM * D_MODEL * 2);
    short* g1_bf  = qkv_bf;  // [8192][4096] bf16 = 64 MB, spans qkv_bf + a_bf

    // preshuffle weights to frag-major bf16 (re-run every launch; ws re-poisoned)
    const int KC1 = D_MODEL / 32;   // 32 chunks for K=1024
    convShuf<<<dim3(D_MODEL / 16, D_MODEL / 128), 256, 0, stream>>>(
        w_q, wqkvP, D_MODEL, D_MODEL);
    convShuf<<<dim3(D_MODEL / 16, D_MODEL / 128), 256, 0, stream>>>(
        w_k, wqkvP + (size_t)64 * KC1 * 512, D_MODEL, D_MODEL);
    convShuf<<<dim3(D_MODEL / 16, D_MODEL / 128), 256, 0, stream>>>(
        w_v, wqkvP + (size_t)128 * KC1 * 512, D_MODEL, D_MODEL);
    convShuf<<<dim3(D_MODEL / 16, D_MODEL / 128), 256, 0, stream>>>(
        w_o, woP, D_MODEL, D_MODEL);
    convShuf<<<dim3(FFN_DIM / 16, D_MODEL / 128), 256, 0, stream>>>(
        w1, w1P, D_MODEL, FFN_DIM);
    convShuf<<<dim3(D_MODEL / 16, FFN_DIM / 128), 256, 0, stream>>>(
        w2, w2P, FFN_DIM, D_MODEL);

    // LN1
    ln_kernel<<<ROWS, 256, 0, stream>>>(x, ln1_g, ln1_b, h_bf);

    // fused QKV projection: [8192][3072]
    gemm128<0><<<dim3(QKV_N / 128, ROWS / 128), 256, 0, stream>>>(
        h_bf, wqkvP, ROWS, QKV_N, D_MODEL, QKV_N,
        nullptr, nullptr, nullptr, qkv_bf);

    // attention (128 q-rows per block)
    attn_mfma<<<dim3(SEQ / 128, NHEAD, BATCH), 256, 0, stream>>>(qkv_bf, a_bf);

    // output projection + bias + residual -> x1 (fp32)
    gemm128<1><<<dim3(D_MODEL / 128, ROWS / 128), 256, 0, stream>>>(
        a_bf, woP, ROWS, D_MODEL, D_MODEL, D_MODEL, b_o, x, x1, nullptr);

    // LN2
    ln_kernel<<<ROWS, 256, 0, stream>>>(x1, ln2_g, ln2_b, h_bf);

    // FFN1 + tanh-GELU -> g1_bf
    gemm128<2><<<dim3(FFN_DIM / 128, ROWS / 128), 256, 0, stream>>>(
        h_bf, w1P, ROWS, FFN_DIM, D_MODEL, FFN_DIM, b1, nullptr, nullptr, g1_bf);

    // FFN2 + bias + residual -> out
    gemm128<1><<<dim3(D_MODEL / 128, ROWS / 128), 256, 0, stream>>>(
        g1_bf, w2P, ROWS, D_MODEL, FFN_DIM, D_MODEL, b2, x1, out, nullptr);
}